// Round 3
// baseline (265.217 us; speedup 1.0000x reference)
//
#include <hip/hip_runtime.h>
#include <stdint.h>

typedef __bf16 bf16_t;
typedef __bf16 bf16x8 __attribute__((ext_vector_type(8)));
typedef float  f32x4  __attribute__((ext_vector_type(4)));

#define AS1 __attribute__((address_space(1)))
#define AS3 __attribute__((address_space(3)))

__device__ __forceinline__ void gld_lds16(const bf16_t* g, void* s) {
  // async global->LDS, 16 bytes per lane; HW dest = wave-uniform base + lane*16
  __builtin_amdgcn_global_load_lds((const AS1 uint32_t*)g, (AS3 uint32_t*)s, 16, 0, 0);
}

// ---------------------------------------------------------------------------
// 0) fp32 -> bf16 canonicalization, all 4 tensors in ONE dispatch.
// ---------------------------------------------------------------------------
__global__ __launch_bounds__(256) void convert_all_kernel(
    const float* __restrict__ X,  const float* __restrict__ Wq,
    const float* __restrict__ Wk, const float* __restrict__ Wv,
    bf16_t* __restrict__ Xc, bf16_t* __restrict__ Wqc,
    bf16_t* __restrict__ Wkc, bf16_t* __restrict__ Wvc) {
  const int blk = blockIdx.x;
  const float* src; bf16_t* dst; int base;
  if (blk < 4096)      { src = X;  dst = Xc;  base = 0;    }
  else if (blk < 4608) { src = Wq; dst = Wqc; base = 4096; }
  else if (blk < 5120) { src = Wk; dst = Wkc; base = 4608; }
  else                 { src = Wv; dst = Wvc; base = 5120; }
  const int i = ((blk - base) * 256 + threadIdx.x) * 8;
  const float4 a = ((const float4*)(src + i))[0];
  const float4 b = ((const float4*)(src + i))[1];
  bf16x8 v;
  v[0] = (bf16_t)a.x; v[1] = (bf16_t)a.y; v[2] = (bf16_t)a.z; v[3] = (bf16_t)a.w;
  v[4] = (bf16_t)b.x; v[5] = (bf16_t)b.y; v[6] = (bf16_t)b.z; v[7] = (bf16_t)b.w;
  *(bf16x8*)(dst + i) = v;
}

// ---------------------------------------------------------------------------
// 128x128 core: C tile of A[M,K]*B[N,K]^T, k in [kBeg,kEnd). 4 waves,
// 64x64 quadrants. XOR-swizzled LDS (conflict-free, verified R4).
// ---------------------------------------------------------------------------
__device__ __forceinline__ void gemm_bt_core(
    const bf16_t* __restrict__ A, int lda,
    const bf16_t* __restrict__ B, int ldb,
    int m0, int n0, int kBeg, int kEnd,
    bf16_t* As, bf16_t* Bs, f32x4 acc[4][4])
{
  const int tid  = threadIdx.x;
  const int lane = tid & 63;
  const int wave = tid >> 6;
  const int wm = (wave >> 1) * 64;
  const int wn = (wave & 1) * 64;
  const int fr = lane & 15;
  const int ck = lane >> 4;

  const int off0 = wave * 2048 + lane * 16;
  const int row0 = wave * 32 + (lane >> 2);
  const int row1 = row0 + 16;
  const int kg   = ((lane & 3) ^ ((row0 >> 1) & 3)) * 8;

  int aoff[4], boff[4];
#pragma unroll
  for (int i = 0; i < 4; ++i) {
    const int ra = wm + i * 16 + fr;
    const int rb = wn + i * 16 + fr;
    aoff[i] = ra * 64 + ((ck ^ ((ra >> 1) & 3)) * 16);
    boff[i] = rb * 64 + ((ck ^ ((rb >> 1) & 3)) * 16);
  }

  for (int kt = kBeg; kt < kEnd; kt += 32) {
    __syncthreads();
    gld_lds16(A + (size_t)(m0 + row0) * lda + kt + kg, (char*)As + off0);
    gld_lds16(A + (size_t)(m0 + row1) * lda + kt + kg, (char*)As + off0 + 1024);
    gld_lds16(B + (size_t)(n0 + row0) * ldb + kt + kg, (char*)Bs + off0);
    gld_lds16(B + (size_t)(n0 + row1) * ldb + kt + kg, (char*)Bs + off0 + 1024);
    __syncthreads();

    bf16x8 af[4], bfv[4];
#pragma unroll
    for (int mi = 0; mi < 4; ++mi)
      af[mi] = *(const bf16x8*)((char*)As + aoff[mi]);
#pragma unroll
    for (int ni = 0; ni < 4; ++ni)
      bfv[ni] = *(const bf16x8*)((char*)Bs + boff[ni]);
#pragma unroll
    for (int mi = 0; mi < 4; ++mi)
#pragma unroll
      for (int ni = 0; ni < 4; ++ni)
        acc[mi][ni] = __builtin_amdgcn_mfma_f32_16x16x32_bf16(
            af[mi], bfv[ni], acc[mi][ni], 0, 0, 0);
  }
}

// ---------------------------------------------------------------------------
// 1) QKV projection: Out[z][8192,1024] = X * W[z]^T (unchanged, ~790 TF)
// ---------------------------------------------------------------------------
__global__ __launch_bounds__(256) void qkv_kernel(
    const bf16_t* __restrict__ X,
    const bf16_t* __restrict__ Wq, const bf16_t* __restrict__ Wk,
    const bf16_t* __restrict__ Wv,
    bf16_t* __restrict__ Q, bf16_t* __restrict__ K, bf16_t* __restrict__ V)
{
  __shared__ bf16_t As[128 * 32];
  __shared__ bf16_t Bs[128 * 32];
  const int m0 = blockIdx.x * 128;
  const int n0 = blockIdx.y * 128;
  const int z  = blockIdx.z;
  const bf16_t* W = (z == 0) ? Wq : (z == 1) ? Wk : Wv;
  bf16_t* Out     = (z == 0) ? Q  : (z == 1) ? K  : V;

  f32x4 acc[4][4] = {};
  gemm_bt_core(X, 1024, W, 1024, m0, n0, 0, 1024, As, Bs, acc);

  const int lane = threadIdx.x & 63;
  const int wave = threadIdx.x >> 6;
  const int wm = (wave >> 1) * 64, wn = (wave & 1) * 64;
#pragma unroll
  for (int mi = 0; mi < 4; ++mi)
#pragma unroll
    for (int r = 0; r < 4; ++r) {
      const int row = m0 + wm + mi * 16 + (lane >> 4) * 4 + r;
#pragma unroll
      for (int ni = 0; ni < 4; ++ni) {
        const int col = n0 + wn + ni * 16 + (lane & 15);
        Out[(size_t)row * 1024 + col] = (bf16_t)acc[mi][ni][r];
      }
    }
}

// ---------------------------------------------------------------------------
// 2) V transpose per batch: Vt[b][d][s] = V[b][s][d]. Runs AFTER scores so
// Vt can alias Q's region (Q dead once scores completes).
// ---------------------------------------------------------------------------
__global__ __launch_bounds__(256) void vt_kernel(
    const bf16_t* __restrict__ V, bf16_t* __restrict__ Vt)
{
  __shared__ bf16_t t[64][66];
  const int b  = blockIdx.z;
  const int s0 = blockIdx.x * 64;
  const int d0 = blockIdx.y * 64;
  const bf16_t* Vb = V  + (size_t)b * 2048 * 1024;
  bf16_t* Vtb      = Vt + (size_t)b * 1024 * 2048;
  const int c = threadIdx.x & 63, r4 = threadIdx.x >> 6;
#pragma unroll
  for (int i = 0; i < 16; ++i) {
    const int r = r4 + i * 4;
    t[r][c] = Vb[(size_t)(s0 + r) * 1024 + d0 + c];
  }
  __syncthreads();
#pragma unroll
  for (int i = 0; i < 16; ++i) {
    const int r = r4 + i * 4;
    Vtb[(size_t)(d0 + r) * 2048 + s0 + c] = t[c][r];
  }
}

// ---------------------------------------------------------------------------
// 3) Fused scores+exp, 128q x 128k causal tiles. R12: ALL 4 batches in one
// dispatch (NB was silently 1 -- 136 blocks = 0.53/CU, half the GPU idle).
// Now 544 active uniform blocks ~2.1/CU, same regime as qkv (793 TF).
// P = exp((Q.K)/32) unnorm bf16 + lp per-128-ktile row sums.
// ---------------------------------------------------------------------------
__global__ __launch_bounds__(256) void scores_exp_kernel(
    const bf16_t* __restrict__ Q, const bf16_t* __restrict__ K,
    bf16_t* __restrict__ P, float* __restrict__ partials)
{
  const int kt = blockIdx.x;          // k-tile (128 wide)
  const int mt = blockIdx.y;          // q-tile (128 wide)
  if (kt > mt) return;                // fully masked tile
  const int m0 = mt * 128;
  const int n0 = kt * 128;
  __shared__ bf16_t As[128 * 32];
  __shared__ bf16_t Bs[128 * 32];
  __shared__ float rowsum[2][128];
  const int batch = blockIdx.z;
  const bf16_t* Qb = Q + (size_t)batch * 2048 * 1024;
  const bf16_t* Kb = K + (size_t)batch * 2048 * 1024;
  bf16_t* Pb = P + (size_t)batch * 2048 * 2048;
  float* lp  = partials + ((size_t)batch * 16 + kt) * 2048;

  f32x4 acc[4][4] = {};
  gemm_bt_core(Qb, 1024, Kb, 1024, m0, n0, 0, 1024, As, Bs, acc);

  const int lane = threadIdx.x & 63;
  const int wave = threadIdx.x >> 6;
  const int wm = (wave >> 1) * 64, wn = (wave & 1) * 64;
  const float c = 0.04508422f;        // log2(e)/32
#pragma unroll
  for (int mi = 0; mi < 4; ++mi)
#pragma unroll
    for (int r = 0; r < 4; ++r) {
      const int lrow = wm + mi * 16 + (lane >> 4) * 4 + r;   // 0..127
      const int row  = m0 + lrow;
      float rs = 0.f;
#pragma unroll
      for (int ni = 0; ni < 4; ++ni) {
        const int col = n0 + wn + ni * 16 + (lane & 15);
        float p = exp2f(acc[mi][ni][r] * c);
        if (col > row) p = 0.f;
        const bf16_t pb = (bf16_t)p;
        Pb[(size_t)row * 2048 + col] = pb;
        rs += (float)pb;              // sum the rounded value pv reads
      }
      rs += __shfl_xor(rs, 1);
      rs += __shfl_xor(rs, 2);
      rs += __shfl_xor(rs, 4);
      rs += __shfl_xor(rs, 8);
      if ((lane & 15) == 0) rowsum[wave & 1][lrow] = rs;  // col-half partial
    }
  __syncthreads();
  if (threadIdx.x < 128)
    lp[m0 + threadIdx.x] = rowsum[0][threadIdx.x] + rowsum[1][threadIdx.x];
}

// ---------------------------------------------------------------------------
// 3.5) Row-sum finalize: Linv[z][row] = 1 / sum_{kt<=row>>7} lp[z][kt][row].
// ---------------------------------------------------------------------------
__global__ __launch_bounds__(256) void lsum_kernel(
    const float* __restrict__ partials, float* __restrict__ Linv)
{
  const int id  = blockIdx.x * 256 + threadIdx.x;  // z*2048 + row
  const int z   = id >> 11;
  const int row = id & 2047;
  const float* lp = partials + (size_t)z * 16 * 2048;
  const int tmax = row >> 7;
  float l = 0.f;
  for (int kt = 0; kt <= tmax; ++kt) l += lp[kt * 2048 + row];
  Linv[id] = 1.f / l;
}

// ---------------------------------------------------------------------------
// 4) PV, 128x128-tile GEMM, all 4 batches (512 blocks = 2/CU, ALL resident
// at t=0). CU c co-hosts linear blocks c and c+256 (dz=2, same y); the
// mt = (z>>1 ? 15-y : y) pairing makes every CU's pair total exactly 17
// k128-tiles. Causality: kEnd = m0+128; scores wrote+masked that range.
// ---------------------------------------------------------------------------
__global__ __launch_bounds__(256) void pv_kernel(
    const bf16_t* __restrict__ P, const bf16_t* __restrict__ Vt,
    const float* __restrict__ Linv, float* __restrict__ out)
{
  __shared__ bf16_t As[128 * 32];
  __shared__ bf16_t Bs[128 * 32];
  const int zb = blockIdx.z;
  const int mt = ((zb >> 1) & 1) ? (15 - blockIdx.y) : blockIdx.y;
  const int m0 = mt * 128;
  const int n0 = blockIdx.x * 128;             // d
  const bf16_t* Pb  = P  + (size_t)zb * 2048 * 2048;
  const bf16_t* Vtb = Vt + (size_t)zb * 1024 * 2048;
  const float* li = Linv + (size_t)zb * 2048;
  float* ob = out + (size_t)zb * 2048 * 1024;

  f32x4 acc[4][4] = {};
  gemm_bt_core(Pb, 2048, Vtb, 2048, m0, n0, 0, m0 + 128, As, Bs, acc);

  const int lane = threadIdx.x & 63;
  const int wave = threadIdx.x >> 6;
  const int wm = (wave >> 1) * 64, wn = (wave & 1) * 64;
#pragma unroll
  for (int mi = 0; mi < 4; ++mi)
#pragma unroll
    for (int r = 0; r < 4; ++r) {
      const int row = m0 + wm + mi * 16 + (lane >> 4) * 4 + r;
      const float inv = li[row];
#pragma unroll
      for (int ni = 0; ni < 4; ++ni) {
        const int col = n0 + wn + ni * 16 + (lane & 15);
        ob[(size_t)row * 1024 + col] = acc[mi][ni][r] * inv;
      }
    }
}

// ---------------------------------------------------------------------------
// R12 workspace plan (liveness-aliased so ALL 4 batches fit one pass):
//   [0,16M)    Q        (dead after scores)  <- Vt aliases here
//   [16,32M)   K        (dead after scores)
//   [32,48M)   V        (dead after vt)
//   [48,64M)   Xc       (dead after qkv)  \
//   [64,70M)   Wq/Wk/Wv (dead after qkv)   }- P[4 batches, 32M) = [48,80M)
//   [70,80M)   fresh P tail                /
//   [80,80.5M) Lp  (4*16*2048 f32)
//   [80.5M,..) Linv (4*2048 f32)
// Order: convert -> qkv -> scores -> lsum -> vt -> pv.
// Total ~80.6 MiB; known available >= 94.1 MiB (NB=1 path worked).
// ---------------------------------------------------------------------------
extern "C" void kernel_launch(void* const* d_in, const int* in_sizes, int n_in,
                              void* d_out, int out_size, void* d_ws, size_t ws_size,
                              hipStream_t stream) {
  const float* X  = (const float*)d_in[0];
  const float* Wq = (const float*)d_in[1];
  const float* Wk = (const float*)d_in[2];
  const float* Wv = (const float*)d_in[3];
  float* out = (float*)d_out;
  char* ws = (char*)d_ws;

  const size_t MB = 1024 * 1024;
  bf16_t* Q    = (bf16_t*)(ws + 0 * MB);
  bf16_t* K    = (bf16_t*)(ws + 16 * MB);
  bf16_t* V    = (bf16_t*)(ws + 32 * MB);
  bf16_t* Xc   = (bf16_t*)(ws + 48 * MB);
  bf16_t* Wqc  = (bf16_t*)(ws + 64 * MB);
  bf16_t* Wkc  = (bf16_t*)(ws + 66 * MB);
  bf16_t* Wvc  = (bf16_t*)(ws + 68 * MB);
  bf16_t* P    = (bf16_t*)(ws + 48 * MB);   // aliases Xc+Wc, extends to 80M
  bf16_t* Vt   = (bf16_t*)(ws + 0 * MB);    // aliases Q (dead after scores)
  float*  Lp   = (float*)(ws + 80 * MB);
  float*  Linv = (float*)(ws + 80 * MB + 512 * 1024);

  convert_all_kernel<<<dim3(5632), 256, 0, stream>>>(X, Wq, Wk, Wv, Xc, Wqc, Wkc, Wvc);
  qkv_kernel<<<dim3(64, 8, 3), 256, 0, stream>>>(Xc, Wqc, Wkc, Wvc, Q, K, V);
  scores_exp_kernel<<<dim3(16, 16, 4), 256, 0, stream>>>(Q, K, P, Lp);
  lsum_kernel<<<dim3(32), 256, 0, stream>>>(Lp, Linv);
  vt_kernel<<<dim3(32, 16, 4), 256, 0, stream>>>(V, Vt);
  pv_kernel<<<dim3(8, 16, 4), 256, 0, stream>>>(P, Vt, Linv, out);
}

// Round 4
// 251.514 us; speedup vs baseline: 1.0545x; 1.0545x over previous
//
#include <hip/hip_runtime.h>
#include <stdint.h>

typedef __bf16 bf16_t;
typedef __bf16 bf16x4 __attribute__((ext_vector_type(4)));
typedef __bf16 bf16x8 __attribute__((ext_vector_type(8)));
typedef float  f32x4  __attribute__((ext_vector_type(4)));

#define AS1 __attribute__((address_space(1)))
#define AS3 __attribute__((address_space(3)))

__device__ __forceinline__ void gld_lds16(const bf16_t* g, void* s) {
  // async global->LDS, 16 bytes per lane; HW dest = wave-uniform base + lane*16
  __builtin_amdgcn_global_load_lds((const AS1 uint32_t*)g, (AS3 uint32_t*)s, 16, 0, 0);
}

// ---------------------------------------------------------------------------
// 0) fp32 -> bf16 canonicalization, all 4 tensors in ONE dispatch.
// ---------------------------------------------------------------------------
__global__ __launch_bounds__(256) void convert_all_kernel(
    const float* __restrict__ X,  const float* __restrict__ Wq,
    const float* __restrict__ Wk, const float* __restrict__ Wv,
    bf16_t* __restrict__ Xc, bf16_t* __restrict__ Wqc,
    bf16_t* __restrict__ Wkc, bf16_t* __restrict__ Wvc) {
  const int blk = blockIdx.x;
  const float* src; bf16_t* dst; int base;
  if (blk < 4096)      { src = X;  dst = Xc;  base = 0;    }
  else if (blk < 4608) { src = Wq; dst = Wqc; base = 4096; }
  else if (blk < 5120) { src = Wk; dst = Wkc; base = 4608; }
  else                 { src = Wv; dst = Wvc; base = 5120; }
  const int i = ((blk - base) * 256 + threadIdx.x) * 8;
  const float4 a = ((const float4*)(src + i))[0];
  const float4 b = ((const float4*)(src + i))[1];
  bf16x8 v;
  v[0] = (bf16_t)a.x; v[1] = (bf16_t)a.y; v[2] = (bf16_t)a.z; v[3] = (bf16_t)a.w;
  v[4] = (bf16_t)b.x; v[5] = (bf16_t)b.y; v[6] = (bf16_t)b.z; v[7] = (bf16_t)b.w;
  *(bf16x8*)(dst + i) = v;
}

// ---------------------------------------------------------------------------
// 128x128 core, R13: BK=64 (was 32). Halves barrier/vmcnt-drain count per
// FLOP: 8 gld + 16 ds_read_b128 + 32 MFMA between barrier pairs. LDS tiles
// [128][64] bf16 (16 KB each). Swizzle: 8 chunks of 16B per row, slot =
// chunk ^ (row&7); staged via inverse-swizzled GLOBAL source (linear LDS
// dest, rule #21), read at slot (kh*4+ck)^(row&7). Worst 2-way = free.
// ---------------------------------------------------------------------------
__device__ __forceinline__ void gemm_bt_core(
    const bf16_t* __restrict__ A, int lda,
    const bf16_t* __restrict__ B, int ldb,
    int m0, int n0, int kBeg, int kEnd,
    bf16_t* As, bf16_t* Bs, f32x4 acc[4][4])
{
  const int lane = threadIdx.x & 63;
  const int wave = threadIdx.x >> 6;
  const int wm = (wave >> 1) * 64;
  const int wn = (wave & 1) * 64;
  const int fr = lane & 15;
  const int ck = lane >> 4;            // 0..3 (16B k-chunk within 32-k half)

  const int srow = lane >> 3;          // staging: 8 lanes per row
  const int sch  = lane & 7;           // 16B chunk within row

  int grow[4], kg[4], dst[4];
#pragma unroll
  for (int j = 0; j < 4; ++j) {
    const int r = wave * 32 + j * 8 + srow;
    grow[j] = r;
    kg[j]   = (sch ^ (r & 7)) * 8;               // inverse-swizzled k offset
    dst[j]  = r * 128 + sch * 16;                // == (wave*32+j*8)*128 + lane*16
  }

  int aoff[4][2], boff[4][2];
#pragma unroll
  for (int i = 0; i < 4; ++i) {
    const int ra = wm + i * 16 + fr;
    const int rb = wn + i * 16 + fr;
#pragma unroll
    for (int kh = 0; kh < 2; ++kh) {
      aoff[i][kh] = ra * 128 + (((kh * 4 + ck) ^ (ra & 7)) * 16);
      boff[i][kh] = rb * 128 + (((kh * 4 + ck) ^ (rb & 7)) * 16);
    }
  }

  for (int kt = kBeg; kt < kEnd; kt += 64) {
    __syncthreads();
#pragma unroll
    for (int j = 0; j < 4; ++j) {
      gld_lds16(A + (size_t)(m0 + grow[j]) * lda + kt + kg[j], (char*)As + dst[j]);
      gld_lds16(B + (size_t)(n0 + grow[j]) * ldb + kt + kg[j], (char*)Bs + dst[j]);
    }
    __syncthreads();

    bf16x8 af[4][2], bfv[4][2];
#pragma unroll
    for (int i = 0; i < 4; ++i)
#pragma unroll
      for (int kh = 0; kh < 2; ++kh) {
        af[i][kh]  = *(const bf16x8*)((char*)As + aoff[i][kh]);
        bfv[i][kh] = *(const bf16x8*)((char*)Bs + boff[i][kh]);
      }
#pragma unroll
    for (int kh = 0; kh < 2; ++kh)
#pragma unroll
      for (int mi = 0; mi < 4; ++mi)
#pragma unroll
        for (int ni = 0; ni < 4; ++ni)
          acc[mi][ni] = __builtin_amdgcn_mfma_f32_16x16x32_bf16(
              af[mi][kh], bfv[ni][kh], acc[mi][ni], 0, 0, 0);
  }
}

// ---------------------------------------------------------------------------
// 1) QKV projection. R13: z=2 writes Vt[b][d][s] DIRECTLY via an LDS
// transpose epilogue (two 64-col rounds through a [64][136] pad buffer
// reusing As/Bs) -- eliminates the V buffer and the whole vt_kernel
// (32 MB traffic + one dispatch boundary).
// ---------------------------------------------------------------------------
__global__ __launch_bounds__(256) void qkv_kernel(
    const bf16_t* __restrict__ X,
    const bf16_t* __restrict__ Wq, const bf16_t* __restrict__ Wk,
    const bf16_t* __restrict__ Wv,
    bf16_t* __restrict__ Q, bf16_t* __restrict__ K, bf16_t* __restrict__ Vt)
{
  __shared__ bf16_t smem[2 * 128 * 64];      // As | Bs (32 KB), reused for t
  bf16_t* As = smem;
  bf16_t* Bs = smem + 128 * 64;
  const int m0 = blockIdx.x * 128;
  const int n0 = blockIdx.y * 128;
  const int z  = blockIdx.z;
  const bf16_t* W = (z == 0) ? Wq : (z == 1) ? Wk : Wv;

  f32x4 acc[4][4] = {};
  gemm_bt_core(X, 1024, W, 1024, m0, n0, 0, 1024, As, Bs, acc);

  const int lane = threadIdx.x & 63;
  const int wave = threadIdx.x >> 6;
  const int wm = (wave >> 1) * 64, wn = (wave & 1) * 64;

  if (z < 2) {
    bf16_t* Out = z ? K : Q;
#pragma unroll
    for (int mi = 0; mi < 4; ++mi)
#pragma unroll
      for (int r = 0; r < 4; ++r) {
        const int row = m0 + wm + mi * 16 + (lane >> 4) * 4 + r;
#pragma unroll
        for (int ni = 0; ni < 4; ++ni) {
          const int col = n0 + wn + ni * 16 + (lane & 15);
          Out[(size_t)row * 1024 + col] = (bf16_t)acc[mi][ni][r];
        }
      }
  } else {
    // Vt[b][d][s]: b = m0>>11, s = m0&2047 .. +127, d = n0 .. +127
    const int b  = m0 >> 11;
    const int s0 = m0 & 2047;
    bf16_t* Vtb = Vt + (size_t)b * 1024 * 2048;
    bf16_t (*t)[136] = (bf16_t(*)[136])smem;   // 64*136*2 = 17.4 KB <= 32 KB
#pragma unroll
    for (int h = 0; h < 2; ++h) {              // column half (d) rounds
      __syncthreads();
      if ((wave & 1) == h) {                   // these 2 waves own cols h*64..+63
#pragma unroll
        for (int mi = 0; mi < 4; ++mi)
#pragma unroll
          for (int ni = 0; ni < 4; ++ni) {
            const int c   = ni * 16 + (lane & 15);          // 0..63
            const int row = wm + mi * 16 + (lane >> 4) * 4; // 0..124, mult of 4
            bf16x4 v;
            v[0] = (bf16_t)acc[mi][ni][0]; v[1] = (bf16_t)acc[mi][ni][1];
            v[2] = (bf16_t)acc[mi][ni][2]; v[3] = (bf16_t)acc[mi][ni][3];
            *(bf16x4*)&t[c][row] = v;          // 8B LDS write, aligned
          }
      }
      __syncthreads();
      // coalesced store: 64 d-rows x 128 s (16 lanes x 16B per d-row)
#pragma unroll
      for (int i = 0; i < 4; ++i) {
        const int u  = threadIdx.x + 256 * i;  // 0..1023
        const int d  = u >> 4;                 // 0..63
        const int ch = u & 15;                 // 16B chunk
        bf16x8 vv = *(const bf16x8*)&t[d][ch * 8];
        *(bf16x8*)(Vtb + (size_t)(n0 + h * 64 + d) * 2048 + s0 + ch * 8) = vv;
      }
    }
  }
}

// ---------------------------------------------------------------------------
// 3) Fused scores+exp, 128q x 128k causal tiles, all 4 batches (544 active
// uniform blocks ~2.1/CU). P = exp((Q.K)/32) unnorm bf16 + lp row sums.
// ---------------------------------------------------------------------------
__global__ __launch_bounds__(256) void scores_exp_kernel(
    const bf16_t* __restrict__ Q, const bf16_t* __restrict__ K,
    bf16_t* __restrict__ P, float* __restrict__ partials)
{
  const int kt = blockIdx.x;          // k-tile (128 wide)
  const int mt = blockIdx.y;          // q-tile (128 wide)
  if (kt > mt) return;                // fully masked tile
  const int m0 = mt * 128;
  const int n0 = kt * 128;
  __shared__ bf16_t smem[2 * 128 * 64];
  __shared__ float rowsum[2][128];
  bf16_t* As = smem;
  bf16_t* Bs = smem + 128 * 64;
  const int batch = blockIdx.z;
  const bf16_t* Qb = Q + (size_t)batch * 2048 * 1024;
  const bf16_t* Kb = K + (size_t)batch * 2048 * 1024;
  bf16_t* Pb = P + (size_t)batch * 2048 * 2048;
  float* lp  = partials + ((size_t)batch * 16 + kt) * 2048;

  f32x4 acc[4][4] = {};
  gemm_bt_core(Qb, 1024, Kb, 1024, m0, n0, 0, 1024, As, Bs, acc);

  const int lane = threadIdx.x & 63;
  const int wave = threadIdx.x >> 6;
  const int wm = (wave >> 1) * 64, wn = (wave & 1) * 64;
  const float c = 0.04508422f;        // log2(e)/32
#pragma unroll
  for (int mi = 0; mi < 4; ++mi)
#pragma unroll
    for (int r = 0; r < 4; ++r) {
      const int lrow = wm + mi * 16 + (lane >> 4) * 4 + r;   // 0..127
      const int row  = m0 + lrow;
      float rs = 0.f;
#pragma unroll
      for (int ni = 0; ni < 4; ++ni) {
        const int col = n0 + wn + ni * 16 + (lane & 15);
        float p = exp2f(acc[mi][ni][r] * c);
        if (col > row) p = 0.f;
        const bf16_t pb = (bf16_t)p;
        Pb[(size_t)row * 2048 + col] = pb;
        rs += (float)pb;              // sum the rounded value pv reads
      }
      rs += __shfl_xor(rs, 1);
      rs += __shfl_xor(rs, 2);
      rs += __shfl_xor(rs, 4);
      rs += __shfl_xor(rs, 8);
      if ((lane & 15) == 0) rowsum[wave & 1][lrow] = rs;  // col-half partial
    }
  __syncthreads();
  if (threadIdx.x < 128)
    lp[m0 + threadIdx.x] = rowsum[0][threadIdx.x] + rowsum[1][threadIdx.x];
}

// ---------------------------------------------------------------------------
// 3.5) Row-sum finalize: Linv[z][row] = 1 / sum_{kt<=row>>7} lp[z][kt][row].
// ---------------------------------------------------------------------------
__global__ __launch_bounds__(256) void lsum_kernel(
    const float* __restrict__ partials, float* __restrict__ Linv)
{
  const int id  = blockIdx.x * 256 + threadIdx.x;  // z*2048 + row
  const int z   = id >> 11;
  const int row = id & 2047;
  const float* lp = partials + (size_t)z * 16 * 2048;
  const int tmax = row >> 7;
  float l = 0.f;
  for (int kt = 0; kt <= tmax; ++kt) l += lp[kt * 2048 + row];
  Linv[id] = 1.f / l;
}

// ---------------------------------------------------------------------------
// 4) PV, 128x128-tile GEMM, all 4 batches (512 blocks = 2/CU, all resident).
// mt pairing keeps每 CU's co-hosted pair at exactly 17 k128-tiles.
// Causality: kEnd = m0+128; scores wrote+masked exactly that range.
// ---------------------------------------------------------------------------
__global__ __launch_bounds__(256) void pv_kernel(
    const bf16_t* __restrict__ P, const bf16_t* __restrict__ Vt,
    const float* __restrict__ Linv, float* __restrict__ out)
{
  __shared__ bf16_t smem[2 * 128 * 64];
  bf16_t* As = smem;
  bf16_t* Bs = smem + 128 * 64;
  const int zb = blockIdx.z;
  const int mt = ((zb >> 1) & 1) ? (15 - blockIdx.y) : blockIdx.y;
  const int m0 = mt * 128;
  const int n0 = blockIdx.x * 128;             // d
  const bf16_t* Pb  = P  + (size_t)zb * 2048 * 2048;
  const bf16_t* Vtb = Vt + (size_t)zb * 1024 * 2048;
  const float* li = Linv + (size_t)zb * 2048;
  float* ob = out + (size_t)zb * 2048 * 1024;

  f32x4 acc[4][4] = {};
  gemm_bt_core(Pb, 2048, Vtb, 2048, m0, n0, 0, m0 + 128, As, Bs, acc);

  const int lane = threadIdx.x & 63;
  const int wave = threadIdx.x >> 6;
  const int wm = (wave >> 1) * 64, wn = (wave & 1) * 64;
#pragma unroll
  for (int mi = 0; mi < 4; ++mi)
#pragma unroll
    for (int r = 0; r < 4; ++r) {
      const int row = m0 + wm + mi * 16 + (lane >> 4) * 4 + r;
      const float inv = li[row];
#pragma unroll
      for (int ni = 0; ni < 4; ++ni) {
        const int col = n0 + wn + ni * 16 + (lane & 15);
        ob[(size_t)row * 1024 + col] = acc[mi][ni][r] * inv;
      }
    }
}

// ---------------------------------------------------------------------------
// R13 workspace (liveness-aliased; V/vt eliminated entirely):
//   [0,16M)    Q     (dead after scores)
//   [16,32M)   K     (dead after scores)
//   [32,48M)   Vt    (written directly by qkv z=2)
//   [48,64M)   Xc    (dead after qkv)  \
//   [64,70M)   W     (dead after qkv)   }- P[4 batches, 32M) = [48,80M)
//   [70,80M)   fresh P tail            /
//   [80,80.5M) Lp;  [80.5M,..) Linv
// Order: convert -> qkv -> scores -> lsum -> pv  (5 dispatches).
// ---------------------------------------------------------------------------
extern "C" void kernel_launch(void* const* d_in, const int* in_sizes, int n_in,
                              void* d_out, int out_size, void* d_ws, size_t ws_size,
                              hipStream_t stream) {
  const float* X  = (const float*)d_in[0];
  const float* Wq = (const float*)d_in[1];
  const float* Wk = (const float*)d_in[2];
  const float* Wv = (const float*)d_in[3];
  float* out = (float*)d_out;
  char* ws = (char*)d_ws;

  const size_t MB = 1024 * 1024;
  bf16_t* Q    = (bf16_t*)(ws + 0 * MB);
  bf16_t* K    = (bf16_t*)(ws + 16 * MB);
  bf16_t* Vt   = (bf16_t*)(ws + 32 * MB);
  bf16_t* Xc   = (bf16_t*)(ws + 48 * MB);
  bf16_t* Wqc  = (bf16_t*)(ws + 64 * MB);
  bf16_t* Wkc  = (bf16_t*)(ws + 66 * MB);
  bf16_t* Wvc  = (bf16_t*)(ws + 68 * MB);
  bf16_t* P    = (bf16_t*)(ws + 48 * MB);   // aliases Xc+W, extends to 80M
  float*  Lp   = (float*)(ws + 80 * MB);
  float*  Linv = (float*)(ws + 80 * MB + 512 * 1024);

  convert_all_kernel<<<dim3(5632), 256, 0, stream>>>(X, Wq, Wk, Wv, Xc, Wqc, Wkc, Wvc);
  qkv_kernel<<<dim3(64, 8, 3), 256, 0, stream>>>(Xc, Wqc, Wkc, Wvc, Q, K, Vt);
  scores_exp_kernel<<<dim3(16, 16, 4), 256, 0, stream>>>(Q, K, P, Lp);
  lsum_kernel<<<dim3(32), 256, 0, stream>>>(Lp, Linv);
  pv_kernel<<<dim3(8, 16, 4), 256, 0, stream>>>(P, Vt, Linv, out);
}

// Round 5
// 250.235 us; speedup vs baseline: 1.0599x; 1.0051x over previous
//
#include <hip/hip_runtime.h>
#include <stdint.h>

typedef __bf16 bf16_t;
typedef __bf16 bf16x4 __attribute__((ext_vector_type(4)));
typedef __bf16 bf16x8 __attribute__((ext_vector_type(8)));
typedef float  f32x4  __attribute__((ext_vector_type(4)));

#define AS1 __attribute__((address_space(1)))
#define AS3 __attribute__((address_space(3)))

__device__ __forceinline__ void gld_lds16(const bf16_t* g, void* s) {
  // async global->LDS, 16 bytes per lane; HW dest = wave-uniform base + lane*16
  __builtin_amdgcn_global_load_lds((const AS1 uint32_t*)g, (AS3 uint32_t*)s, 16, 0, 0);
}

// ---------------------------------------------------------------------------
// 0) fp32 -> bf16 canonicalization, all 4 tensors in ONE dispatch.
// ---------------------------------------------------------------------------
__global__ __launch_bounds__(256) void convert_all_kernel(
    const float* __restrict__ X,  const float* __restrict__ Wq,
    const float* __restrict__ Wk, const float* __restrict__ Wv,
    bf16_t* __restrict__ Xc, bf16_t* __restrict__ Wqc,
    bf16_t* __restrict__ Wkc, bf16_t* __restrict__ Wvc) {
  const int blk = blockIdx.x;
  const float* src; bf16_t* dst; int base;
  if (blk < 4096)      { src = X;  dst = Xc;  base = 0;    }
  else if (blk < 4608) { src = Wq; dst = Wqc; base = 4096; }
  else if (blk < 5120) { src = Wk; dst = Wkc; base = 4608; }
  else                 { src = Wv; dst = Wvc; base = 5120; }
  const int i = ((blk - base) * 256 + threadIdx.x) * 8;
  const float4 a = ((const float4*)(src + i))[0];
  const float4 b = ((const float4*)(src + i))[1];
  bf16x8 v;
  v[0] = (bf16_t)a.x; v[1] = (bf16_t)a.y; v[2] = (bf16_t)a.z; v[3] = (bf16_t)a.w;
  v[4] = (bf16_t)b.x; v[5] = (bf16_t)b.y; v[6] = (bf16_t)b.z; v[7] = (bf16_t)b.w;
  *(bf16x8*)(dst + i) = v;
}

// ---------------------------------------------------------------------------
// 128x128 core, R14: BK=32 (R3 layout/swizzle, measured 0 bank conflicts)
// + T3-minimum 2-phase DOUBLE BUFFER + T5 setprio.
//   prologue: STAGE(buf0); syncthreads
//   iter:     STAGE(buf^1, kt+32); ds_read(buf); MFMA; syncthreads; swap
// One barrier per k-step (was 2); the vmcnt(0) inside __syncthreads now
// lands ~(16 ds_read + 16 MFMA) after load-issue instead of immediately,
// hiding L2/L3 latency that 2-blocks/CU TLP cannot.
// As/Bs are each 2 buffers of 128x32 bf16 (8 KB); total 32 KB.
// ---------------------------------------------------------------------------
__device__ __forceinline__ void gemm_bt_core(
    const bf16_t* __restrict__ A, int lda,
    const bf16_t* __restrict__ B, int ldb,
    int m0, int n0, int kBeg, int kEnd,
    bf16_t* As, bf16_t* Bs, f32x4 acc[4][4])
{
  const int lane = threadIdx.x & 63;
  const int wave = threadIdx.x >> 6;
  const int wm = (wave >> 1) * 64;
  const int wn = (wave & 1) * 64;
  const int fr = lane & 15;
  const int ck = lane >> 4;

  const int off0 = wave * 2048 + lane * 16;     // bytes within one 8KB buffer
  const int row0 = wave * 32 + (lane >> 2);
  const int row1 = row0 + 16;
  const int kg   = ((lane & 3) ^ ((row0 >> 1) & 3)) * 8;

  const bf16_t* Ar0 = A + (size_t)(m0 + row0) * lda + kg;
  const bf16_t* Ar1 = A + (size_t)(m0 + row1) * lda + kg;
  const bf16_t* Br0 = B + (size_t)(n0 + row0) * ldb + kg;
  const bf16_t* Br1 = B + (size_t)(n0 + row1) * ldb + kg;

  int aoff[4], boff[4];
#pragma unroll
  for (int i = 0; i < 4; ++i) {
    const int ra = wm + i * 16 + fr;
    const int rb = wn + i * 16 + fr;
    aoff[i] = ra * 64 + ((ck ^ ((ra >> 1) & 3)) * 16);
    boff[i] = rb * 64 + ((ck ^ ((rb >> 1) & 3)) * 16);
  }

  // prologue: stage first k-slab into buffer 0
  gld_lds16(Ar0 + kBeg, (char*)As + off0);
  gld_lds16(Ar1 + kBeg, (char*)As + off0 + 1024);
  gld_lds16(Br0 + kBeg, (char*)Bs + off0);
  gld_lds16(Br1 + kBeg, (char*)Bs + off0 + 1024);
  __syncthreads();

  int cur = 0;
  for (int kt = kBeg; kt < kEnd; kt += 32) {
    const int nxt = cur ^ 1;
    if (kt + 32 < kEnd) {               // issue next-slab loads FIRST
      gld_lds16(Ar0 + kt + 32, (char*)As + nxt * 8192 + off0);
      gld_lds16(Ar1 + kt + 32, (char*)As + nxt * 8192 + off0 + 1024);
      gld_lds16(Br0 + kt + 32, (char*)Bs + nxt * 8192 + off0);
      gld_lds16(Br1 + kt + 32, (char*)Bs + nxt * 8192 + off0 + 1024);
    }
    bf16x8 af[4], bfv[4];
#pragma unroll
    for (int mi = 0; mi < 4; ++mi)
      af[mi] = *(const bf16x8*)((char*)As + cur * 8192 + aoff[mi]);
#pragma unroll
    for (int ni = 0; ni < 4; ++ni)
      bfv[ni] = *(const bf16x8*)((char*)Bs + cur * 8192 + boff[ni]);
    __builtin_amdgcn_s_setprio(1);
#pragma unroll
    for (int mi = 0; mi < 4; ++mi)
#pragma unroll
      for (int ni = 0; ni < 4; ++ni)
        acc[mi][ni] = __builtin_amdgcn_mfma_f32_16x16x32_bf16(
            af[mi], bfv[ni], acc[mi][ni], 0, 0, 0);
    __builtin_amdgcn_s_setprio(0);
    __syncthreads();                    // vmcnt(0)+lgkmcnt(0)+barrier
    cur = nxt;
  }
}

// ---------------------------------------------------------------------------
// 1) QKV projection. z=2 writes Vt[b][d][s] DIRECTLY via an LDS transpose
// epilogue (two 64-col rounds through a [64][136] pad buffer reusing smem).
// ---------------------------------------------------------------------------
__global__ __launch_bounds__(256) void qkv_kernel(
    const bf16_t* __restrict__ X,
    const bf16_t* __restrict__ Wq, const bf16_t* __restrict__ Wk,
    const bf16_t* __restrict__ Wv,
    bf16_t* __restrict__ Q, bf16_t* __restrict__ K, bf16_t* __restrict__ Vt)
{
  __shared__ bf16_t smem[4 * 128 * 32];      // 32 KB: As dbuf | Bs dbuf
  bf16_t* As = smem;
  bf16_t* Bs = smem + 2 * 128 * 32;
  const int m0 = blockIdx.x * 128;
  const int n0 = blockIdx.y * 128;
  const int z  = blockIdx.z;
  const bf16_t* W = (z == 0) ? Wq : (z == 1) ? Wk : Wv;

  f32x4 acc[4][4] = {};
  gemm_bt_core(X, 1024, W, 1024, m0, n0, 0, 1024, As, Bs, acc);

  const int lane = threadIdx.x & 63;
  const int wave = threadIdx.x >> 6;
  const int wm = (wave >> 1) * 64, wn = (wave & 1) * 64;

  if (z < 2) {
    bf16_t* Out = z ? K : Q;
#pragma unroll
    for (int mi = 0; mi < 4; ++mi)
#pragma unroll
      for (int r = 0; r < 4; ++r) {
        const int row = m0 + wm + mi * 16 + (lane >> 4) * 4 + r;
#pragma unroll
        for (int ni = 0; ni < 4; ++ni) {
          const int col = n0 + wn + ni * 16 + (lane & 15);
          Out[(size_t)row * 1024 + col] = (bf16_t)acc[mi][ni][r];
        }
      }
  } else {
    // Vt[b][d][s]: b = m0>>11, s = m0&2047 .. +127, d = n0 .. +127
    const int b  = m0 >> 11;
    const int s0 = m0 & 2047;
    bf16_t* Vtb = Vt + (size_t)b * 1024 * 2048;
    bf16_t (*t)[136] = (bf16_t(*)[136])smem;   // 64*136*2 = 17.4 KB <= 32 KB
#pragma unroll
    for (int h = 0; h < 2; ++h) {              // column half (d) rounds
      __syncthreads();
      if ((wave & 1) == h) {                   // these 2 waves own cols h*64..+63
#pragma unroll
        for (int mi = 0; mi < 4; ++mi)
#pragma unroll
          for (int ni = 0; ni < 4; ++ni) {
            const int c   = ni * 16 + (lane & 15);          // 0..63
            const int row = wm + mi * 16 + (lane >> 4) * 4; // 0..124, mult of 4
            bf16x4 v;
            v[0] = (bf16_t)acc[mi][ni][0]; v[1] = (bf16_t)acc[mi][ni][1];
            v[2] = (bf16_t)acc[mi][ni][2]; v[3] = (bf16_t)acc[mi][ni][3];
            *(bf16x4*)&t[c][row] = v;          // 8B LDS write, aligned
          }
      }
      __syncthreads();
      // coalesced store: 64 d-rows x 128 s (16 lanes x 16B per d-row)
#pragma unroll
      for (int i = 0; i < 4; ++i) {
        const int u  = threadIdx.x + 256 * i;  // 0..1023
        const int d  = u >> 4;                 // 0..63
        const int ch = u & 15;                 // 16B chunk
        bf16x8 vv = *(const bf16x8*)&t[d][ch * 8];
        *(bf16x8*)(Vtb + (size_t)(n0 + h * 64 + d) * 2048 + s0 + ch * 8) = vv;
      }
    }
  }
}

// ---------------------------------------------------------------------------
// 3) Fused scores+exp, 128q x 128k causal tiles, all 4 batches (544 active
// uniform blocks ~2.1/CU). P = exp((Q.K)/32) unnorm bf16 + lp row sums.
// ---------------------------------------------------------------------------
__global__ __launch_bounds__(256) void scores_exp_kernel(
    const bf16_t* __restrict__ Q, const bf16_t* __restrict__ K,
    bf16_t* __restrict__ P, float* __restrict__ partials)
{
  const int kt = blockIdx.x;          // k-tile (128 wide)
  const int mt = blockIdx.y;          // q-tile (128 wide)
  if (kt > mt) return;                // fully masked tile
  const int m0 = mt * 128;
  const int n0 = kt * 128;
  __shared__ bf16_t smem[4 * 128 * 32];
  __shared__ float rowsum[2][128];
  bf16_t* As = smem;
  bf16_t* Bs = smem + 2 * 128 * 32;
  const int batch = blockIdx.z;
  const bf16_t* Qb = Q + (size_t)batch * 2048 * 1024;
  const bf16_t* Kb = K + (size_t)batch * 2048 * 1024;
  bf16_t* Pb = P + (size_t)batch * 2048 * 2048;
  float* lp  = partials + ((size_t)batch * 16 + kt) * 2048;

  f32x4 acc[4][4] = {};
  gemm_bt_core(Qb, 1024, Kb, 1024, m0, n0, 0, 1024, As, Bs, acc);

  const int lane = threadIdx.x & 63;
  const int wave = threadIdx.x >> 6;
  const int wm = (wave >> 1) * 64, wn = (wave & 1) * 64;
  const float c = 0.04508422f;        // log2(e)/32
#pragma unroll
  for (int mi = 0; mi < 4; ++mi)
#pragma unroll
    for (int r = 0; r < 4; ++r) {
      const int lrow = wm + mi * 16 + (lane >> 4) * 4 + r;   // 0..127
      const int row  = m0 + lrow;
      float rs = 0.f;
#pragma unroll
      for (int ni = 0; ni < 4; ++ni) {
        const int col = n0 + wn + ni * 16 + (lane & 15);
        float p = exp2f(acc[mi][ni][r] * c);
        if (col > row) p = 0.f;
        const bf16_t pb = (bf16_t)p;
        Pb[(size_t)row * 2048 + col] = pb;
        rs += (float)pb;              // sum the rounded value pv reads
      }
      rs += __shfl_xor(rs, 1);
      rs += __shfl_xor(rs, 2);
      rs += __shfl_xor(rs, 4);
      rs += __shfl_xor(rs, 8);
      if ((lane & 15) == 0) rowsum[wave & 1][lrow] = rs;  // col-half partial
    }
  __syncthreads();
  if (threadIdx.x < 128)
    lp[m0 + threadIdx.x] = rowsum[0][threadIdx.x] + rowsum[1][threadIdx.x];
}

// ---------------------------------------------------------------------------
// 3.5) Row-sum finalize: Linv[z][row] = 1 / sum_{kt<=row>>7} lp[z][kt][row].
// ---------------------------------------------------------------------------
__global__ __launch_bounds__(256) void lsum_kernel(
    const float* __restrict__ partials, float* __restrict__ Linv)
{
  const int id  = blockIdx.x * 256 + threadIdx.x;  // z*2048 + row
  const int z   = id >> 11;
  const int row = id & 2047;
  const float* lp = partials + (size_t)z * 16 * 2048;
  const int tmax = row >> 7;
  float l = 0.f;
  for (int kt = 0; kt <= tmax; ++kt) l += lp[kt * 2048 + row];
  Linv[id] = 1.f / l;
}

// ---------------------------------------------------------------------------
// 4) PV, 128x128-tile GEMM, all 4 batches (512 blocks = 2/CU, all resident).
// mt pairing keeps each CU's co-hosted pair at exactly 17 k128-tiles.
// Causality: kEnd = m0+128; scores wrote+masked exactly that range.
// ---------------------------------------------------------------------------
__global__ __launch_bounds__(256) void pv_kernel(
    const bf16_t* __restrict__ P, const bf16_t* __restrict__ Vt,
    const float* __restrict__ Linv, float* __restrict__ out)
{
  __shared__ bf16_t smem[4 * 128 * 32];
  bf16_t* As = smem;
  bf16_t* Bs = smem + 2 * 128 * 32;
  const int zb = blockIdx.z;
  const int mt = ((zb >> 1) & 1) ? (15 - blockIdx.y) : blockIdx.y;
  const int m0 = mt * 128;
  const int n0 = blockIdx.x * 128;             // d
  const bf16_t* Pb  = P  + (size_t)zb * 2048 * 2048;
  const bf16_t* Vtb = Vt + (size_t)zb * 1024 * 2048;
  const float* li = Linv + (size_t)zb * 2048;
  float* ob = out + (size_t)zb * 2048 * 1024;

  f32x4 acc[4][4] = {};
  gemm_bt_core(Pb, 2048, Vtb, 2048, m0, n0, 0, m0 + 128, As, Bs, acc);

  const int lane = threadIdx.x & 63;
  const int wave = threadIdx.x >> 6;
  const int wm = (wave >> 1) * 64, wn = (wave & 1) * 64;
#pragma unroll
  for (int mi = 0; mi < 4; ++mi)
#pragma unroll
    for (int r = 0; r < 4; ++r) {
      const int row = m0 + wm + mi * 16 + (lane >> 4) * 4 + r;
      const float inv = li[row];
#pragma unroll
      for (int ni = 0; ni < 4; ++ni) {
        const int col = n0 + wn + ni * 16 + (lane & 15);
        ob[(size_t)row * 1024 + col] = acc[mi][ni][r] * inv;
      }
    }
}

// ---------------------------------------------------------------------------
// R14 workspace (liveness-aliased; V/vt eliminated):
//   [0,16M)    Q     (dead after scores)
//   [16,32M)   K     (dead after scores)
//   [32,48M)   Vt    (written directly by qkv z=2)
//   [48,64M)   Xc    (dead after qkv)  \
//   [64,70M)   W     (dead after qkv)   }- P[4 batches, 32M) = [48,80M)
//   [70,80M)   fresh P tail            /
//   [80,80.5M) Lp;  [80.5M,..) Linv
// Order: convert -> qkv -> scores -> lsum -> pv  (5 dispatches).
// ---------------------------------------------------------------------------
extern "C" void kernel_launch(void* const* d_in, const int* in_sizes, int n_in,
                              void* d_out, int out_size, void* d_ws, size_t ws_size,
                              hipStream_t stream) {
  const float* X  = (const float*)d_in[0];
  const float* Wq = (const float*)d_in[1];
  const float* Wk = (const float*)d_in[2];
  const float* Wv = (const float*)d_in[3];
  float* out = (float*)d_out;
  char* ws = (char*)d_ws;

  const size_t MB = 1024 * 1024;
  bf16_t* Q    = (bf16_t*)(ws + 0 * MB);
  bf16_t* K    = (bf16_t*)(ws + 16 * MB);
  bf16_t* Vt   = (bf16_t*)(ws + 32 * MB);
  bf16_t* Xc   = (bf16_t*)(ws + 48 * MB);
  bf16_t* Wqc  = (bf16_t*)(ws + 64 * MB);
  bf16_t* Wkc  = (bf16_t*)(ws + 66 * MB);
  bf16_t* Wvc  = (bf16_t*)(ws + 68 * MB);
  bf16_t* P    = (bf16_t*)(ws + 48 * MB);   // aliases Xc+W, extends to 80M
  float*  Lp   = (float*)(ws + 80 * MB);
  float*  Linv = (float*)(ws + 80 * MB + 512 * 1024);

  convert_all_kernel<<<dim3(5632), 256, 0, stream>>>(X, Wq, Wk, Wv, Xc, Wqc, Wkc, Wvc);
  qkv_kernel<<<dim3(64, 8, 3), 256, 0, stream>>>(Xc, Wqc, Wkc, Wvc, Q, K, Vt);
  scores_exp_kernel<<<dim3(16, 16, 4), 256, 0, stream>>>(Q, K, P, Lp);
  lsum_kernel<<<dim3(32), 256, 0, stream>>>(Lp, Linv);
  pv_kernel<<<dim3(8, 16, 4), 256, 0, stream>>>(P, Vt, Linv, out);
}

// Round 6
// 241.165 us; speedup vs baseline: 1.0997x; 1.0376x over previous
//
#include <hip/hip_runtime.h>
#include <stdint.h>

typedef __bf16 bf16_t;
typedef __bf16 bf16x4 __attribute__((ext_vector_type(4)));
typedef __bf16 bf16x8 __attribute__((ext_vector_type(8)));
typedef float  f32x4  __attribute__((ext_vector_type(4)));

#define AS1 __attribute__((address_space(1)))
#define AS3 __attribute__((address_space(3)))

__device__ __forceinline__ void gld_lds16(const bf16_t* g, void* s) {
  // async global->LDS, 16 bytes per lane; HW dest = wave-uniform base + lane*16
  __builtin_amdgcn_global_load_lds((const AS1 uint32_t*)g, (AS3 uint32_t*)s, 16, 0, 0);
}

// ---------------------------------------------------------------------------
// 0) fp32 -> bf16 canonicalization, all 4 tensors in ONE dispatch.
// ---------------------------------------------------------------------------
__global__ __launch_bounds__(256) void convert_all_kernel(
    const float* __restrict__ X,  const float* __restrict__ Wq,
    const float* __restrict__ Wk, const float* __restrict__ Wv,
    bf16_t* __restrict__ Xc, bf16_t* __restrict__ Wqc,
    bf16_t* __restrict__ Wkc, bf16_t* __restrict__ Wvc) {
  const int blk = blockIdx.x;
  const float* src; bf16_t* dst; int base;
  if (blk < 4096)      { src = X;  dst = Xc;  base = 0;    }
  else if (blk < 4608) { src = Wq; dst = Wqc; base = 4096; }
  else if (blk < 5120) { src = Wk; dst = Wkc; base = 4608; }
  else                 { src = Wv; dst = Wvc; base = 5120; }
  const int i = ((blk - base) * 256 + threadIdx.x) * 8;
  const float4 a = ((const float4*)(src + i))[0];
  const float4 b = ((const float4*)(src + i))[1];
  bf16x8 v;
  v[0] = (bf16_t)a.x; v[1] = (bf16_t)a.y; v[2] = (bf16_t)a.z; v[3] = (bf16_t)a.w;
  v[4] = (bf16_t)b.x; v[5] = (bf16_t)b.y; v[6] = (bf16_t)b.z; v[7] = (bf16_t)b.w;
  *(bf16x8*)(dst + i) = v;
}

// ---------------------------------------------------------------------------
// 128x128 core, R15: double-buffered BK=32 with COUNTED vmcnt (T4) instead
// of __syncthreads' vmcnt(0) drain (R5 post-mortem: the drain at each step's
// end nullified the prefetch -- the m97/m218 lesson).
// Per k-step:
//   STAGE(nxt buf, 4x gld)            <- stays in flight a FULL step
//   s_waitcnt vmcnt(4)                <- only prev-iter loads must be done
//   s_barrier                         <- cur buffer complete for ALL waves
//   ds_read(cur) -> 16 MFMA
//   s_waitcnt lgkmcnt(0); s_barrier   <- readers retired; cur may be reused
// No vmcnt(0) in the steady loop. sched_barrier(0) fences pin the schedule;
// all waits carry "memory" so gld/ds ops can't migrate across.
// ---------------------------------------------------------------------------
__device__ __forceinline__ void gemm_bt_core(
    const bf16_t* __restrict__ A, int lda,
    const bf16_t* __restrict__ B, int ldb,
    int m0, int n0, int kBeg, int kEnd,
    bf16_t* As, bf16_t* Bs, f32x4 acc[4][4])
{
  const int lane = threadIdx.x & 63;
  const int wave = threadIdx.x >> 6;
  const int wm = (wave >> 1) * 64;
  const int wn = (wave & 1) * 64;
  const int fr = lane & 15;
  const int ck = lane >> 4;

  const int off0 = wave * 2048 + lane * 16;     // bytes within one 8KB buffer
  const int row0 = wave * 32 + (lane >> 2);
  const int row1 = row0 + 16;
  const int kg   = ((lane & 3) ^ ((row0 >> 1) & 3)) * 8;

  const bf16_t* Ar0 = A + (size_t)(m0 + row0) * lda + kg;
  const bf16_t* Ar1 = A + (size_t)(m0 + row1) * lda + kg;
  const bf16_t* Br0 = B + (size_t)(n0 + row0) * ldb + kg;
  const bf16_t* Br1 = B + (size_t)(n0 + row1) * ldb + kg;

  int aoff[4], boff[4];
#pragma unroll
  for (int i = 0; i < 4; ++i) {
    const int ra = wm + i * 16 + fr;
    const int rb = wn + i * 16 + fr;
    aoff[i] = ra * 64 + ((ck ^ ((ra >> 1) & 3)) * 16);
    boff[i] = rb * 64 + ((ck ^ ((rb >> 1) & 3)) * 16);
  }

  // prologue: stage first k-slab into buffer 0 (4 loads in flight)
  gld_lds16(Ar0 + kBeg, (char*)As + off0);
  gld_lds16(Ar1 + kBeg, (char*)As + off0 + 1024);
  gld_lds16(Br0 + kBeg, (char*)Bs + off0);
  gld_lds16(Br1 + kBeg, (char*)Bs + off0 + 1024);

  int cur = 0;
  for (int kt = kBeg; kt < kEnd; kt += 32) {
    const int nxt = cur ^ 1;
    if (kt + 32 < kEnd) {               // STAGE next slab first (depth-1)
      gld_lds16(Ar0 + kt + 32, (char*)As + nxt * 8192 + off0);
      gld_lds16(Ar1 + kt + 32, (char*)As + nxt * 8192 + off0 + 1024);
      gld_lds16(Br0 + kt + 32, (char*)Bs + nxt * 8192 + off0);
      gld_lds16(Br1 + kt + 32, (char*)Bs + nxt * 8192 + off0 + 1024);
      asm volatile("s_waitcnt vmcnt(4)" ::: "memory");  // cur-buf loads done
    } else {
      asm volatile("s_waitcnt vmcnt(0)" ::: "memory");  // final slab: drain
    }
    __builtin_amdgcn_sched_barrier(0);
    __builtin_amdgcn_s_barrier();       // cur complete for all waves
    __builtin_amdgcn_sched_barrier(0);

    bf16x8 af[4], bfv[4];
#pragma unroll
    for (int mi = 0; mi < 4; ++mi)
      af[mi] = *(const bf16x8*)((char*)As + cur * 8192 + aoff[mi]);
#pragma unroll
    for (int ni = 0; ni < 4; ++ni)
      bfv[ni] = *(const bf16x8*)((char*)Bs + cur * 8192 + boff[ni]);
    __builtin_amdgcn_s_setprio(1);
#pragma unroll
    for (int mi = 0; mi < 4; ++mi)
#pragma unroll
      for (int ni = 0; ni < 4; ++ni)
        acc[mi][ni] = __builtin_amdgcn_mfma_f32_16x16x32_bf16(
            af[mi], bfv[ni], acc[mi][ni], 0, 0, 0);
    __builtin_amdgcn_s_setprio(0);

    asm volatile("s_waitcnt lgkmcnt(0)" ::: "memory");  // ds_reads retired
    __builtin_amdgcn_sched_barrier(0);
    __builtin_amdgcn_s_barrier();       // cur may now be overwritten
    __builtin_amdgcn_sched_barrier(0);
    cur = nxt;
  }
}

// ---------------------------------------------------------------------------
// 1) QKV projection. z=2 writes Vt[b][d][s] DIRECTLY via an LDS transpose
// epilogue (two 64-col rounds through a [64][136] pad buffer reusing smem).
// ---------------------------------------------------------------------------
__global__ __launch_bounds__(256) void qkv_kernel(
    const bf16_t* __restrict__ X,
    const bf16_t* __restrict__ Wq, const bf16_t* __restrict__ Wk,
    const bf16_t* __restrict__ Wv,
    bf16_t* __restrict__ Q, bf16_t* __restrict__ K, bf16_t* __restrict__ Vt)
{
  __shared__ bf16_t smem[4 * 128 * 32];      // 32 KB: As dbuf | Bs dbuf
  bf16_t* As = smem;
  bf16_t* Bs = smem + 2 * 128 * 32;
  const int m0 = blockIdx.x * 128;
  const int n0 = blockIdx.y * 128;
  const int z  = blockIdx.z;
  const bf16_t* W = (z == 0) ? Wq : (z == 1) ? Wk : Wv;

  f32x4 acc[4][4] = {};
  gemm_bt_core(X, 1024, W, 1024, m0, n0, 0, 1024, As, Bs, acc);

  const int lane = threadIdx.x & 63;
  const int wave = threadIdx.x >> 6;
  const int wm = (wave >> 1) * 64, wn = (wave & 1) * 64;

  if (z < 2) {
    bf16_t* Out = z ? K : Q;
#pragma unroll
    for (int mi = 0; mi < 4; ++mi)
#pragma unroll
      for (int r = 0; r < 4; ++r) {
        const int row = m0 + wm + mi * 16 + (lane >> 4) * 4 + r;
#pragma unroll
        for (int ni = 0; ni < 4; ++ni) {
          const int col = n0 + wn + ni * 16 + (lane & 15);
          Out[(size_t)row * 1024 + col] = (bf16_t)acc[mi][ni][r];
        }
      }
  } else {
    // Vt[b][d][s]: b = m0>>11, s = m0&2047 .. +127, d = n0 .. +127
    const int b  = m0 >> 11;
    const int s0 = m0 & 2047;
    bf16_t* Vtb = Vt + (size_t)b * 1024 * 2048;
    bf16_t (*t)[136] = (bf16_t(*)[136])smem;   // 64*136*2 = 17.4 KB <= 32 KB
#pragma unroll
    for (int h = 0; h < 2; ++h) {              // column half (d) rounds
      __syncthreads();
      if ((wave & 1) == h) {                   // these 2 waves own cols h*64..+63
#pragma unroll
        for (int mi = 0; mi < 4; ++mi)
#pragma unroll
          for (int ni = 0; ni < 4; ++ni) {
            const int c   = ni * 16 + (lane & 15);          // 0..63
            const int row = wm + mi * 16 + (lane >> 4) * 4; // 0..124, mult of 4
            bf16x4 v;
            v[0] = (bf16_t)acc[mi][ni][0]; v[1] = (bf16_t)acc[mi][ni][1];
            v[2] = (bf16_t)acc[mi][ni][2]; v[3] = (bf16_t)acc[mi][ni][3];
            *(bf16x4*)&t[c][row] = v;          // 8B LDS write, aligned
          }
      }
      __syncthreads();
      // coalesced store: 64 d-rows x 128 s (16 lanes x 16B per d-row)
#pragma unroll
      for (int i = 0; i < 4; ++i) {
        const int u  = threadIdx.x + 256 * i;  // 0..1023
        const int d  = u >> 4;                 // 0..63
        const int ch = u & 15;                 // 16B chunk
        bf16x8 vv = *(const bf16x8*)&t[d][ch * 8];
        *(bf16x8*)(Vtb + (size_t)(n0 + h * 64 + d) * 2048 + s0 + ch * 8) = vv;
      }
    }
  }
}

// ---------------------------------------------------------------------------
// 3) Fused scores+exp, 128q x 128k causal tiles, all 4 batches (544 active
// uniform blocks ~2.1/CU). P = exp((Q.K)/32) unnorm bf16 + lp row sums.
// ---------------------------------------------------------------------------
__global__ __launch_bounds__(256) void scores_exp_kernel(
    const bf16_t* __restrict__ Q, const bf16_t* __restrict__ K,
    bf16_t* __restrict__ P, float* __restrict__ partials)
{
  const int kt = blockIdx.x;          // k-tile (128 wide)
  const int mt = blockIdx.y;          // q-tile (128 wide)
  if (kt > mt) return;                // fully masked tile
  const int m0 = mt * 128;
  const int n0 = kt * 128;
  __shared__ bf16_t smem[4 * 128 * 32];
  __shared__ float rowsum[2][128];
  bf16_t* As = smem;
  bf16_t* Bs = smem + 2 * 128 * 32;
  const int batch = blockIdx.z;
  const bf16_t* Qb = Q + (size_t)batch * 2048 * 1024;
  const bf16_t* Kb = K + (size_t)batch * 2048 * 1024;
  bf16_t* Pb = P + (size_t)batch * 2048 * 2048;
  float* lp  = partials + ((size_t)batch * 16 + kt) * 2048;

  f32x4 acc[4][4] = {};
  gemm_bt_core(Qb, 1024, Kb, 1024, m0, n0, 0, 1024, As, Bs, acc);

  const int lane = threadIdx.x & 63;
  const int wave = threadIdx.x >> 6;
  const int wm = (wave >> 1) * 64, wn = (wave & 1) * 64;
  const float c = 0.04508422f;        // log2(e)/32
#pragma unroll
  for (int mi = 0; mi < 4; ++mi)
#pragma unroll
    for (int r = 0; r < 4; ++r) {
      const int lrow = wm + mi * 16 + (lane >> 4) * 4 + r;   // 0..127
      const int row  = m0 + lrow;
      float rs = 0.f;
#pragma unroll
      for (int ni = 0; ni < 4; ++ni) {
        const int col = n0 + wn + ni * 16 + (lane & 15);
        float p = exp2f(acc[mi][ni][r] * c);
        if (col > row) p = 0.f;
        const bf16_t pb = (bf16_t)p;
        Pb[(size_t)row * 2048 + col] = pb;
        rs += (float)pb;              // sum the rounded value pv reads
      }
      rs += __shfl_xor(rs, 1);
      rs += __shfl_xor(rs, 2);
      rs += __shfl_xor(rs, 4);
      rs += __shfl_xor(rs, 8);
      if ((lane & 15) == 0) rowsum[wave & 1][lrow] = rs;  // col-half partial
    }
  __syncthreads();
  if (threadIdx.x < 128)
    lp[m0 + threadIdx.x] = rowsum[0][threadIdx.x] + rowsum[1][threadIdx.x];
}

// ---------------------------------------------------------------------------
// 3.5) Row-sum finalize: Linv[z][row] = 1 / sum_{kt<=row>>7} lp[z][kt][row].
// ---------------------------------------------------------------------------
__global__ __launch_bounds__(256) void lsum_kernel(
    const float* __restrict__ partials, float* __restrict__ Linv)
{
  const int id  = blockIdx.x * 256 + threadIdx.x;  // z*2048 + row
  const int z   = id >> 11;
  const int row = id & 2047;
  const float* lp = partials + (size_t)z * 16 * 2048;
  const int tmax = row >> 7;
  float l = 0.f;
  for (int kt = 0; kt <= tmax; ++kt) l += lp[kt * 2048 + row];
  Linv[id] = 1.f / l;
}

// ---------------------------------------------------------------------------
// 4) PV, 128x128-tile GEMM, all 4 batches (512 blocks = 2/CU, all resident).
// mt pairing keeps each CU's co-hosted pair at exactly 17 k128-tiles.
// Causality: kEnd = m0+128; scores wrote+masked exactly that range.
// ---------------------------------------------------------------------------
__global__ __launch_bounds__(256) void pv_kernel(
    const bf16_t* __restrict__ P, const bf16_t* __restrict__ Vt,
    const float* __restrict__ Linv, float* __restrict__ out)
{
  __shared__ bf16_t smem[4 * 128 * 32];
  bf16_t* As = smem;
  bf16_t* Bs = smem + 2 * 128 * 32;
  const int zb = blockIdx.z;
  const int mt = ((zb >> 1) & 1) ? (15 - blockIdx.y) : blockIdx.y;
  const int m0 = mt * 128;
  const int n0 = blockIdx.x * 128;             // d
  const bf16_t* Pb  = P  + (size_t)zb * 2048 * 2048;
  const bf16_t* Vtb = Vt + (size_t)zb * 1024 * 2048;
  const float* li = Linv + (size_t)zb * 2048;
  float* ob = out + (size_t)zb * 2048 * 1024;

  f32x4 acc[4][4] = {};
  gemm_bt_core(Pb, 2048, Vtb, 2048, m0, n0, 0, m0 + 128, As, Bs, acc);

  const int lane = threadIdx.x & 63;
  const int wave = threadIdx.x >> 6;
  const int wm = (wave >> 1) * 64, wn = (wave & 1) * 64;
#pragma unroll
  for (int mi = 0; mi < 4; ++mi)
#pragma unroll
    for (int r = 0; r < 4; ++r) {
      const int row = m0 + wm + mi * 16 + (lane >> 4) * 4 + r;
      const float inv = li[row];
#pragma unroll
      for (int ni = 0; ni < 4; ++ni) {
        const int col = n0 + wn + ni * 16 + (lane & 15);
        ob[(size_t)row * 1024 + col] = acc[mi][ni][r] * inv;
      }
    }
}

// ---------------------------------------------------------------------------
// R15 workspace (liveness-aliased; V/vt eliminated):
//   [0,16M)    Q     (dead after scores)
//   [16,32M)   K     (dead after scores)
//   [32,48M)   Vt    (written directly by qkv z=2)
//   [48,64M)   Xc    (dead after qkv)  \
//   [64,70M)   W     (dead after qkv)   }- P[4 batches, 32M) = [48,80M)
//   [70,80M)   fresh P tail            /
//   [80,80.5M) Lp;  [80.5M,..) Linv
// Order: convert -> qkv -> scores -> lsum -> pv  (5 dispatches).
// ---------------------------------------------------------------------------
extern "C" void kernel_launch(void* const* d_in, const int* in_sizes, int n_in,
                              void* d_out, int out_size, void* d_ws, size_t ws_size,
                              hipStream_t stream) {
  const float* X  = (const float*)d_in[0];
  const float* Wq = (const float*)d_in[1];
  const float* Wk = (const float*)d_in[2];
  const float* Wv = (const float*)d_in[3];
  float* out = (float*)d_out;
  char* ws = (char*)d_ws;

  const size_t MB = 1024 * 1024;
  bf16_t* Q    = (bf16_t*)(ws + 0 * MB);
  bf16_t* K    = (bf16_t*)(ws + 16 * MB);
  bf16_t* Vt   = (bf16_t*)(ws + 32 * MB);
  bf16_t* Xc   = (bf16_t*)(ws + 48 * MB);
  bf16_t* Wqc  = (bf16_t*)(ws + 64 * MB);
  bf16_t* Wkc  = (bf16_t*)(ws + 66 * MB);
  bf16_t* Wvc  = (bf16_t*)(ws + 68 * MB);
  bf16_t* P    = (bf16_t*)(ws + 48 * MB);   // aliases Xc+W, extends to 80M
  float*  Lp   = (float*)(ws + 80 * MB);
  float*  Linv = (float*)(ws + 80 * MB + 512 * 1024);

  convert_all_kernel<<<dim3(5632), 256, 0, stream>>>(X, Wq, Wk, Wv, Xc, Wqc, Wkc, Wvc);
  qkv_kernel<<<dim3(64, 8, 3), 256, 0, stream>>>(Xc, Wqc, Wkc, Wvc, Q, K, Vt);
  scores_exp_kernel<<<dim3(16, 16, 4), 256, 0, stream>>>(Q, K, P, Lp);
  lsum_kernel<<<dim3(32), 256, 0, stream>>>(Lp, Linv);
  pv_kernel<<<dim3(8, 16, 4), 256, 0, stream>>>(P, Vt, Linv, out);
}

// Round 7
// 231.927 us; speedup vs baseline: 1.1435x; 1.0398x over previous
//
#include <hip/hip_runtime.h>
#include <stdint.h>

typedef __bf16 bf16_t;
typedef __bf16 bf16x4 __attribute__((ext_vector_type(4)));
typedef __bf16 bf16x8 __attribute__((ext_vector_type(8)));
typedef float  f32x4  __attribute__((ext_vector_type(4)));

#define AS1 __attribute__((address_space(1)))
#define AS3 __attribute__((address_space(3)))

__device__ __forceinline__ void gld_lds16(const bf16_t* g, void* s) {
  // async global->LDS, 16 bytes per lane; HW dest = wave-uniform base + lane*16
  __builtin_amdgcn_global_load_lds((const AS1 uint32_t*)g, (AS3 uint32_t*)s, 16, 0, 0);
}

// ---------------------------------------------------------------------------
// 0) fp32 -> bf16 canonicalization, all 4 tensors in ONE dispatch.
// ---------------------------------------------------------------------------
__global__ __launch_bounds__(256) void convert_all_kernel(
    const float* __restrict__ X,  const float* __restrict__ Wq,
    const float* __restrict__ Wk, const float* __restrict__ Wv,
    bf16_t* __restrict__ Xc, bf16_t* __restrict__ Wqc,
    bf16_t* __restrict__ Wkc, bf16_t* __restrict__ Wvc) {
  const int blk = blockIdx.x;
  const float* src; bf16_t* dst; int base;
  if (blk < 4096)      { src = X;  dst = Xc;  base = 0;    }
  else if (blk < 4608) { src = Wq; dst = Wqc; base = 4096; }
  else if (blk < 5120) { src = Wk; dst = Wkc; base = 4608; }
  else                 { src = Wv; dst = Wvc; base = 5120; }
  const int i = ((blk - base) * 256 + threadIdx.x) * 8;
  const float4 a = ((const float4*)(src + i))[0];
  const float4 b = ((const float4*)(src + i))[1];
  bf16x8 v;
  v[0] = (bf16_t)a.x; v[1] = (bf16_t)a.y; v[2] = (bf16_t)a.z; v[3] = (bf16_t)a.w;
  v[4] = (bf16_t)b.x; v[5] = (bf16_t)b.y; v[6] = (bf16_t)b.z; v[7] = (bf16_t)b.w;
  *(bf16x8*)(dst + i) = v;
}

// ---------------------------------------------------------------------------
// R16: 256x256 8-wave core (template geometry: BM=BN=256, BK=64, 512 thr,
// wave grid 2Mx4N, per-wave 128x64 out = acc[8][4]). Double-buffered LDS
// (A,B each 2x32KB = 128 KB total), counted vmcnt(8) -- next-tile's 8 loads
// stay in flight across the whole compute phase (R6 discipline, m218 T4).
// 64 MFMA/wave between barrier pairs (4x the 128^2 core) = 2x intensity.
// Swizzle: row of 64 bf16 = 8 chunks of 16B; LDS slot s holds global chunk
// s^(row&7); staged via inverse-swizzled global source (linear LDS dest,
// rule #21); read at slot (ks*4+ck)^(row&7)  == byte XOR ks*64.
// ---------------------------------------------------------------------------
__device__ __forceinline__ void gemm256_core(
    const bf16_t* __restrict__ A, int lda,
    const bf16_t* __restrict__ B, int ldb,
    int m0, int n0, int kEnd,
    char* lds, f32x4 acc[8][4])
{
  const int tid  = threadIdx.x;
  const int lane = tid & 63;
  const int wave = tid >> 6;           // 0..7
  const int wm = (wave >> 2) * 128;    // 0 / 128
  const int wn = (wave & 3) * 64;      // 0 / 64 / 128 / 192
  const int fr = lane & 15;
  const int ck = lane >> 4;            // 16B chunk within 32-k slice

  // staging: thread t covers (row = j*64 + (t>>3), chunk = t&7), j = 0..3
  const int srow = tid >> 3;           // 0..63
  const int sch  = tid & 7;
  const int kgs  = (sch ^ (srow & 7)) * 8;   // inverse-swizzled k elem offset
  const int sdst = srow * 128 + sch * 16;    // linear LDS dest (lane*16 form)

  const bf16_t* Ar = A + (size_t)(m0 + srow) * lda + kgs;
  const bf16_t* Br = B + (size_t)(n0 + srow) * ldb + kgs;

  int aoffs[8], boffs[4];
#pragma unroll
  for (int mi = 0; mi < 8; ++mi) {
    const int ra = wm + mi * 16 + fr;
    aoffs[mi] = ra * 128 + ((ck ^ (ra & 7)) * 16);
  }
#pragma unroll
  for (int ni = 0; ni < 4; ++ni) {
    const int rb = wn + ni * 16 + fr;
    boffs[ni] = rb * 128 + ((ck ^ (rb & 7)) * 16);
  }

  // prologue: stage K-tile 0 into buffer 0 (8 loads in flight)
#pragma unroll
  for (int j = 0; j < 4; ++j) {
    gld_lds16(Ar + (size_t)(j * 64) * lda, lds + j * 8192 + sdst);
    gld_lds16(Br + (size_t)(j * 64) * ldb, lds + 65536 + j * 8192 + sdst);
  }

  const int NK = kEnd >> 6;
  int cur = 0;
  for (int t = 0; t < NK; ++t) {
    const int nxt = cur ^ 1;
    if (t + 1 < NK) {                  // STAGE next K-tile first
      const bf16_t* An = Ar + (t + 1) * 64;
      const bf16_t* Bn = Br + (t + 1) * 64;
#pragma unroll
      for (int j = 0; j < 4; ++j) {
        gld_lds16(An + (size_t)(j * 64) * lda, lds + nxt * 32768 + j * 8192 + sdst);
        gld_lds16(Bn + (size_t)(j * 64) * ldb, lds + 65536 + nxt * 32768 + j * 8192 + sdst);
      }
      asm volatile("s_waitcnt vmcnt(8)" ::: "memory");  // cur's 8 retired
    } else {
      asm volatile("s_waitcnt vmcnt(0)" ::: "memory");  // final tile: drain
    }
    __builtin_amdgcn_sched_barrier(0);
    __builtin_amdgcn_s_barrier();      // cur complete for all waves
    __builtin_amdgcn_sched_barrier(0);

    const char* Ab = lds + cur * 32768;
    const char* Bb = lds + 65536 + cur * 32768;
#pragma unroll
    for (int ks = 0; ks < 2; ++ks) {
      bf16x8 af[8], bfv[4];
#pragma unroll
      for (int mi = 0; mi < 8; ++mi)
        af[mi] = *(const bf16x8*)(Ab + (aoffs[mi] ^ (ks * 64)));
#pragma unroll
      for (int ni = 0; ni < 4; ++ni)
        bfv[ni] = *(const bf16x8*)(Bb + (boffs[ni] ^ (ks * 64)));
      asm volatile("s_waitcnt lgkmcnt(0)" ::: "memory");
      __builtin_amdgcn_sched_barrier(0);
      __builtin_amdgcn_s_setprio(1);
#pragma unroll
      for (int mi = 0; mi < 8; ++mi)
#pragma unroll
        for (int ni = 0; ni < 4; ++ni)
          acc[mi][ni] = __builtin_amdgcn_mfma_f32_16x16x32_bf16(
              af[mi], bfv[ni], acc[mi][ni], 0, 0, 0);
      __builtin_amdgcn_s_setprio(0);
    }
    asm volatile("s_waitcnt lgkmcnt(0)" ::: "memory");  // readers retired
    __builtin_amdgcn_sched_barrier(0);
    __builtin_amdgcn_s_barrier();      // cur may now be overwritten
    __builtin_amdgcn_sched_barrier(0);
    cur = nxt;
  }
}

// ---------------------------------------------------------------------------
// 128x128 4-wave core (R6 counted-vmcnt) -- kept for pv, whose grid needs
// 512 balanced blocks (256^2 would give only 128 imbalanced ones).
// ---------------------------------------------------------------------------
__device__ __forceinline__ void gemm_bt_core(
    const bf16_t* __restrict__ A, int lda,
    const bf16_t* __restrict__ B, int ldb,
    int m0, int n0, int kBeg, int kEnd,
    bf16_t* As, bf16_t* Bs, f32x4 acc[4][4])
{
  const int lane = threadIdx.x & 63;
  const int wave = threadIdx.x >> 6;
  const int wm = (wave >> 1) * 64;
  const int wn = (wave & 1) * 64;
  const int fr = lane & 15;
  const int ck = lane >> 4;

  const int off0 = wave * 2048 + lane * 16;     // bytes within one 8KB buffer
  const int row0 = wave * 32 + (lane >> 2);
  const int row1 = row0 + 16;
  const int kg   = ((lane & 3) ^ ((row0 >> 1) & 3)) * 8;

  const bf16_t* Ar0 = A + (size_t)(m0 + row0) * lda + kg;
  const bf16_t* Ar1 = A + (size_t)(m0 + row1) * lda + kg;
  const bf16_t* Br0 = B + (size_t)(n0 + row0) * ldb + kg;
  const bf16_t* Br1 = B + (size_t)(n0 + row1) * ldb + kg;

  int aoff[4], boff[4];
#pragma unroll
  for (int i = 0; i < 4; ++i) {
    const int ra = wm + i * 16 + fr;
    const int rb = wn + i * 16 + fr;
    aoff[i] = ra * 64 + ((ck ^ ((ra >> 1) & 3)) * 16);
    boff[i] = rb * 64 + ((ck ^ ((rb >> 1) & 3)) * 16);
  }

  gld_lds16(Ar0 + kBeg, (char*)As + off0);
  gld_lds16(Ar1 + kBeg, (char*)As + off0 + 1024);
  gld_lds16(Br0 + kBeg, (char*)Bs + off0);
  gld_lds16(Br1 + kBeg, (char*)Bs + off0 + 1024);

  int cur = 0;
  for (int kt = kBeg; kt < kEnd; kt += 32) {
    const int nxt = cur ^ 1;
    if (kt + 32 < kEnd) {
      gld_lds16(Ar0 + kt + 32, (char*)As + nxt * 8192 + off0);
      gld_lds16(Ar1 + kt + 32, (char*)As + nxt * 8192 + off0 + 1024);
      gld_lds16(Br0 + kt + 32, (char*)Bs + nxt * 8192 + off0);
      gld_lds16(Br1 + kt + 32, (char*)Bs + nxt * 8192 + off0 + 1024);
      asm volatile("s_waitcnt vmcnt(4)" ::: "memory");
    } else {
      asm volatile("s_waitcnt vmcnt(0)" ::: "memory");
    }
    __builtin_amdgcn_sched_barrier(0);
    __builtin_amdgcn_s_barrier();
    __builtin_amdgcn_sched_barrier(0);

    bf16x8 af[4], bfv[4];
#pragma unroll
    for (int mi = 0; mi < 4; ++mi)
      af[mi] = *(const bf16x8*)((char*)As + cur * 8192 + aoff[mi]);
#pragma unroll
    for (int ni = 0; ni < 4; ++ni)
      bfv[ni] = *(const bf16x8*)((char*)Bs + cur * 8192 + boff[ni]);
    __builtin_amdgcn_s_setprio(1);
#pragma unroll
    for (int mi = 0; mi < 4; ++mi)
#pragma unroll
      for (int ni = 0; ni < 4; ++ni)
        acc[mi][ni] = __builtin_amdgcn_mfma_f32_16x16x32_bf16(
            af[mi], bfv[ni], acc[mi][ni], 0, 0, 0);
    __builtin_amdgcn_s_setprio(0);

    asm volatile("s_waitcnt lgkmcnt(0)" ::: "memory");
    __builtin_amdgcn_sched_barrier(0);
    __builtin_amdgcn_s_barrier();
    __builtin_amdgcn_sched_barrier(0);
    cur = nxt;
  }
}

// ---------------------------------------------------------------------------
// 1) QKV projection, 256^2 core. Grid (32,4,3)=384 blocks @ 1/CU (128KB LDS)
// -> 1.5 rounds. z=2 writes Vt[b][d][s] directly: 4 rounds of 64 d-cols
// through a [64][264] LDS pad buffer (reuses the 128KB smem).
// ---------------------------------------------------------------------------
__global__ __launch_bounds__(512) void qkv_kernel(
    const bf16_t* __restrict__ X,
    const bf16_t* __restrict__ Wq, const bf16_t* __restrict__ Wk,
    const bf16_t* __restrict__ Wv,
    bf16_t* __restrict__ Q, bf16_t* __restrict__ K, bf16_t* __restrict__ Vt)
{
  __shared__ bf16_t smem[65536];             // 128 KB
  const int m0 = blockIdx.x * 256;
  const int n0 = blockIdx.y * 256;
  const int z  = blockIdx.z;
  const bf16_t* W = (z == 0) ? Wq : (z == 1) ? Wk : Wv;

  f32x4 acc[8][4] = {};
  gemm256_core(X, 1024, W, 1024, m0, n0, 1024, (char*)smem, acc);

  const int tid  = threadIdx.x;
  const int lane = tid & 63;
  const int wave = tid >> 6;
  const int wm = (wave >> 2) * 128, wn = (wave & 3) * 64;

  if (z < 2) {
    bf16_t* Out = z ? K : Q;
#pragma unroll
    for (int mi = 0; mi < 8; ++mi)
#pragma unroll
      for (int r = 0; r < 4; ++r) {
        const int row = m0 + wm + mi * 16 + (lane >> 4) * 4 + r;
#pragma unroll
        for (int ni = 0; ni < 4; ++ni) {
          const int col = n0 + wn + ni * 16 + (lane & 15);
          Out[(size_t)row * 1024 + col] = (bf16_t)acc[mi][ni][r];
        }
      }
  } else {
    // Vt[b][d][s]: b = m0>>11, s = m0&2047 .. +255, d = n0 .. +255
    const int b  = m0 >> 11;
    const int s0 = m0 & 2047;
    bf16_t* Vtb = Vt + (size_t)b * 1024 * 2048;
    bf16_t (*tb)[264] = (bf16_t(*)[264])smem;  // 64*264*2 = 33.8 KB
#pragma unroll
    for (int h = 0; h < 4; ++h) {              // d-quarter rounds
      __syncthreads();
      if ((wave & 3) == h) {                   // waves h, h+4: cols h*64..+63
#pragma unroll
        for (int mi = 0; mi < 8; ++mi)
#pragma unroll
          for (int ni = 0; ni < 4; ++ni) {
            const int c    = ni * 16 + (lane & 15);          // 0..63
            const int rowl = wm + mi * 16 + (lane >> 4) * 4; // 0..252, mult 4
            bf16x4 v;
            v[0] = (bf16_t)acc[mi][ni][0]; v[1] = (bf16_t)acc[mi][ni][1];
            v[2] = (bf16_t)acc[mi][ni][2]; v[3] = (bf16_t)acc[mi][ni][3];
            *(bf16x4*)&tb[c][rowl] = v;        // 8B LDS write, aligned
          }
      }
      __syncthreads();
      // store 64 d-rows x 256 s: 2048 16B-chunks over 512 threads
#pragma unroll
      for (int i = 0; i < 4; ++i) {
        const int idx = tid + 512 * i;         // 0..2047
        const int d   = idx >> 5;              // 0..63
        const int ch  = idx & 31;              // 16B chunk
        bf16x8 vv = *(const bf16x8*)&tb[d][ch * 8];
        *(bf16x8*)(Vtb + (size_t)(n0 + h * 64 + d) * 2048 + s0 + ch * 8) = vv;
      }
    }
  }
}

// ---------------------------------------------------------------------------
// 3) Fused scores+exp, 256q x 256k causal tiles, 256^2 core. Grid (8,8,4),
// keep kt<=mt: 144 uniform full-K blocks (single round, ~2x per-CU rate vs
// the 128^2 core). P = exp((Q.K)/32) unnorm bf16; lp keeps the per-128-k
// slice layout pv/lsum expect (each block writes slices 2kt and 2kt+1).
// ---------------------------------------------------------------------------
__global__ __launch_bounds__(512) void scores_exp_kernel(
    const bf16_t* __restrict__ Q, const bf16_t* __restrict__ K,
    bf16_t* __restrict__ P, float* __restrict__ partials)
{
  const int kt = blockIdx.x;          // k-tile (256 wide)
  const int mt = blockIdx.y;          // q-tile (256 wide)
  if (kt > mt) return;                // fully masked tile
  const int m0 = mt * 256;
  const int n0 = kt * 256;
  __shared__ bf16_t smem[65536];
  const int batch = blockIdx.z;
  const bf16_t* Qb = Q + (size_t)batch * 2048 * 1024;
  const bf16_t* Kb = K + (size_t)batch * 2048 * 1024;
  bf16_t* Pb = P + (size_t)batch * 2048 * 2048;
  float* lp  = partials + (size_t)batch * 16 * 2048;

  f32x4 acc[8][4] = {};
  gemm256_core(Qb, 1024, Kb, 1024, m0, n0, 1024, (char*)smem, acc);

  const int tid  = threadIdx.x;
  const int lane = tid & 63;
  const int wave = tid >> 6;
  const int wm = (wave >> 2) * 128, wn = (wave & 3) * 64;
  float (*rowsum)[256] = (float(*)[256])smem;  // reuse LDS (post-loop barrier)
  const float c = 0.04508422f;        // log2(e)/32
#pragma unroll
  for (int mi = 0; mi < 8; ++mi)
#pragma unroll
    for (int r = 0; r < 4; ++r) {
      const int lrow = wm + mi * 16 + (lane >> 4) * 4 + r;   // 0..255
      const int row  = m0 + lrow;
      float rs = 0.f;
#pragma unroll
      for (int ni = 0; ni < 4; ++ni) {
        const int col = n0 + wn + ni * 16 + (lane & 15);
        float p = exp2f(acc[mi][ni][r] * c);
        if (col > row) p = 0.f;
        const bf16_t pb = (bf16_t)p;
        Pb[(size_t)row * 2048 + col] = pb;
        rs += (float)pb;              // sum the rounded value pv reads
      }
      rs += __shfl_xor(rs, 1);
      rs += __shfl_xor(rs, 2);
      rs += __shfl_xor(rs, 4);
      rs += __shfl_xor(rs, 8);
      if ((lane & 15) == 0) rowsum[wave & 3][lrow] = rs;  // col-quarter part
    }
  __syncthreads();
  {
    const int row = tid & 255;        // 0..255
    const int s   = tid >> 8;         // 0..1 -> 128-k slice within tile
    lp[(size_t)(2 * kt + s) * 2048 + m0 + row] =
        rowsum[2 * s][row] + rowsum[2 * s + 1][row];
  }
}

// ---------------------------------------------------------------------------
// 3.5) Row-sum finalize: Linv[z][row] = 1 / sum_{kt<=row>>7} lp[z][kt][row].
// ---------------------------------------------------------------------------
__global__ __launch_bounds__(256) void lsum_kernel(
    const float* __restrict__ partials, float* __restrict__ Linv)
{
  const int id  = blockIdx.x * 256 + threadIdx.x;  // z*2048 + row
  const int z   = id >> 11;
  const int row = id & 2047;
  const float* lp = partials + (size_t)z * 16 * 2048;
  const int tmax = row >> 7;
  float l = 0.f;
  for (int kt = 0; kt <= tmax; ++kt) l += lp[kt * 2048 + row];
  Linv[id] = 1.f / l;
}

// ---------------------------------------------------------------------------
// 4) PV, 128x128-tile GEMM, all 4 batches (512 blocks = 2/CU, all resident).
// mt pairing keeps each CU's co-hosted pair at exactly 17 k128-tiles.
// Causality: kEnd = m0+128; scores wrote+masked exactly that range.
// ---------------------------------------------------------------------------
__global__ __launch_bounds__(256) void pv_kernel(
    const bf16_t* __restrict__ P, const bf16_t* __restrict__ Vt,
    const float* __restrict__ Linv, float* __restrict__ out)
{
  __shared__ bf16_t smem[4 * 128 * 32];
  bf16_t* As = smem;
  bf16_t* Bs = smem + 2 * 128 * 32;
  const int zb = blockIdx.z;
  const int mt = ((zb >> 1) & 1) ? (15 - blockIdx.y) : blockIdx.y;
  const int m0 = mt * 128;
  const int n0 = blockIdx.x * 128;             // d
  const bf16_t* Pb  = P  + (size_t)zb * 2048 * 2048;
  const bf16_t* Vtb = Vt + (size_t)zb * 1024 * 2048;
  const float* li = Linv + (size_t)zb * 2048;
  float* ob = out + (size_t)zb * 2048 * 1024;

  f32x4 acc[4][4] = {};
  gemm_bt_core(Pb, 2048, Vtb, 2048, m0, n0, 0, m0 + 128, As, Bs, acc);

  const int lane = threadIdx.x & 63;
  const int wave = threadIdx.x >> 6;
  const int wm = (wave >> 1) * 64, wn = (wave & 1) * 64;
#pragma unroll
  for (int mi = 0; mi < 4; ++mi)
#pragma unroll
    for (int r = 0; r < 4; ++r) {
      const int row = m0 + wm + mi * 16 + (lane >> 4) * 4 + r;
      const float inv = li[row];
#pragma unroll
      for (int ni = 0; ni < 4; ++ni) {
        const int col = n0 + wn + ni * 16 + (lane & 15);
        ob[(size_t)row * 1024 + col] = acc[mi][ni][r] * inv;
      }
    }
}

// ---------------------------------------------------------------------------
// R16 workspace (liveness-aliased; V/vt eliminated):
//   [0,16M)    Q     (dead after scores)
//   [16,32M)   K     (dead after scores)
//   [32,48M)   Vt    (written directly by qkv z=2)
//   [48,64M)   Xc    (dead after qkv)  \
//   [64,70M)   W     (dead after qkv)   }- P[4 batches, 32M) = [48,80M)
//   [70,80M)   fresh P tail            /
//   [80,80.5M) Lp;  [80.5M,..) Linv
// Order: convert -> qkv -> scores -> lsum -> pv  (5 dispatches).
// ---------------------------------------------------------------------------
extern "C" void kernel_launch(void* const* d_in, const int* in_sizes, int n_in,
                              void* d_out, int out_size, void* d_ws, size_t ws_size,
                              hipStream_t stream) {
  const float* X  = (const float*)d_in[0];
  const float* Wq = (const float*)d_in[1];
  const float* Wk = (const float*)d_in[2];
  const float* Wv = (const float*)d_in[3];
  float* out = (float*)d_out;
  char* ws = (char*)d_ws;

  const size_t MB = 1024 * 1024;
  bf16_t* Q    = (bf16_t*)(ws + 0 * MB);
  bf16_t* K    = (bf16_t*)(ws + 16 * MB);
  bf16_t* Vt   = (bf16_t*)(ws + 32 * MB);
  bf16_t* Xc   = (bf16_t*)(ws + 48 * MB);
  bf16_t* Wqc  = (bf16_t*)(ws + 64 * MB);
  bf16_t* Wkc  = (bf16_t*)(ws + 66 * MB);
  bf16_t* Wvc  = (bf16_t*)(ws + 68 * MB);
  bf16_t* P    = (bf16_t*)(ws + 48 * MB);   // aliases Xc+W, extends to 80M
  float*  Lp   = (float*)(ws + 80 * MB);
  float*  Linv = (float*)(ws + 80 * MB + 512 * 1024);

  convert_all_kernel<<<dim3(5632), 256, 0, stream>>>(X, Wq, Wk, Wv, Xc, Wqc, Wkc, Wvc);
  qkv_kernel<<<dim3(32, 4, 3), 512, 0, stream>>>(Xc, Wqc, Wkc, Wvc, Q, K, Vt);
  scores_exp_kernel<<<dim3(8, 8, 4), 512, 0, stream>>>(Q, K, P, Lp);
  lsum_kernel<<<dim3(32), 256, 0, stream>>>(Lp, Linv);
  pv_kernel<<<dim3(8, 16, 4), 256, 0, stream>>>(P, Vt, Linv, out);
}

// Round 8
// 231.478 us; speedup vs baseline: 1.1458x; 1.0019x over previous
//
#include <hip/hip_runtime.h>
#include <stdint.h>

typedef __bf16 bf16_t;
typedef __bf16 bf16x4 __attribute__((ext_vector_type(4)));
typedef __bf16 bf16x8 __attribute__((ext_vector_type(8)));
typedef float  f32x4  __attribute__((ext_vector_type(4)));

#define AS1 __attribute__((address_space(1)))
#define AS3 __attribute__((address_space(3)))

__device__ __forceinline__ void gld_lds16(const bf16_t* g, void* s) {
  // async global->LDS, 16 bytes per lane; HW dest = wave-uniform base + lane*16
  __builtin_amdgcn_global_load_lds((const AS1 uint32_t*)g, (AS3 uint32_t*)s, 16, 0, 0);
}

// ---------------------------------------------------------------------------
// 0) fp32 -> bf16 canonicalization, all 4 tensors in ONE dispatch.
// ---------------------------------------------------------------------------
__global__ __launch_bounds__(256) void convert_all_kernel(
    const float* __restrict__ X,  const float* __restrict__ Wq,
    const float* __restrict__ Wk, const float* __restrict__ Wv,
    bf16_t* __restrict__ Xc, bf16_t* __restrict__ Wqc,
    bf16_t* __restrict__ Wkc, bf16_t* __restrict__ Wvc) {
  const int blk = blockIdx.x;
  const float* src; bf16_t* dst; int base;
  if (blk < 4096)      { src = X;  dst = Xc;  base = 0;    }
  else if (blk < 4608) { src = Wq; dst = Wqc; base = 4096; }
  else if (blk < 5120) { src = Wk; dst = Wkc; base = 4608; }
  else                 { src = Wv; dst = Wvc; base = 5120; }
  const int i = ((blk - base) * 256 + threadIdx.x) * 8;
  const float4 a = ((const float4*)(src + i))[0];
  const float4 b = ((const float4*)(src + i))[1];
  bf16x8 v;
  v[0] = (bf16_t)a.x; v[1] = (bf16_t)a.y; v[2] = (bf16_t)a.z; v[3] = (bf16_t)a.w;
  v[4] = (bf16_t)b.x; v[5] = (bf16_t)b.y; v[6] = (bf16_t)b.z; v[7] = (bf16_t)b.w;
  *(bf16x8*)(dst + i) = v;
}

// ---------------------------------------------------------------------------
// R18 THIN core: 128x256 tile, BK=32, 8 waves (512 thr), wave grid 2M x 4N,
// per-wave 64x64 out = acc[4][4] (proven shape). Double-buffered LDS:
// As 2x8KB + Bs 2x16KB = 48 KB -> 2-3 blocks/CU co-residency (vs 128KB fat
// core's 1/CU). Counted vmcnt(3) discipline (R6-verified). Swizzle: row of
// 32 bf16 = 4 chunks of 16B, LDS slot s holds global chunk s^(row&3);
// staged via inverse-swizzled global source (linear LDS dest, rule #21);
// ds_read at slot ck^(row&3) -> 2-way worst = free.
// ---------------------------------------------------------------------------
__device__ __forceinline__ void gemm_thin_core(
    const bf16_t* __restrict__ A, int lda,
    const bf16_t* __restrict__ B, int ldb,
    int m0, int n0, int kEnd,
    char* lds, f32x4 acc[4][4])
{
  const int tid  = threadIdx.x;
  const int lane = tid & 63;
  const int wave = tid >> 6;           // 0..7
  const int wm = (wave >> 2) * 64;     // 0 / 64
  const int wn = (wave & 3) * 64;      // 0 / 64 / 128 / 192
  const int fr = lane & 15;
  const int ck = lane >> 4;            // 16B chunk of the 32-k slice

  // staging: thread t -> A slot (row=t>>2, ch=t&3); B rows t>>2 and t>>2+128
  const int srow = tid >> 2;           // 0..127
  const int sch  = tid & 3;
  const int kg   = (sch ^ (srow & 3)) * 8;     // inverse-swizzled k offset
  const int dstA = srow * 64 + sch * 16;       // bytes within 8KB A buffer
  const int dstB = dstA;                        // same form within 16KB B buf

  const bf16_t* Ar  = A + (size_t)(m0 + srow) * lda + kg;
  const bf16_t* Br0 = B + (size_t)(n0 + srow) * ldb + kg;
  const bf16_t* Br1 = B + (size_t)(n0 + srow + 128) * ldb + kg;  // (srow+128)&3 == srow&3

  int aoff[4], boff[4];
#pragma unroll
  for (int i = 0; i < 4; ++i) {
    const int ra = wm + i * 16 + fr;           // 0..127
    const int rb = wn + i * 16 + fr;           // 0..255
    aoff[i] = ra * 64 + ((ck ^ (ra & 3)) * 16);
    boff[i] = rb * 64 + ((ck ^ (rb & 3)) * 16);
  }

  // LDS map: [0,16K) = As dbuf (2x8K); [16K,48K) = Bs dbuf (2x16K)
  // prologue: stage k-slab 0 into buffer 0 (3 loads in flight)
  gld_lds16(Ar, lds + dstA);
  gld_lds16(Br0, lds + 16384 + dstB);
  gld_lds16(Br1, lds + 16384 + 8192 + dstB);

  const int NK = kEnd >> 5;
  int cur = 0;
  for (int t = 0; t < NK; ++t) {
    const int nxt = cur ^ 1;
    if (t + 1 < NK) {                  // STAGE next slab first (depth-1)
      const int ko = (t + 1) * 32;
      gld_lds16(Ar + ko, lds + nxt * 8192 + dstA);
      gld_lds16(Br0 + ko, lds + 16384 + nxt * 16384 + dstB);
      gld_lds16(Br1 + ko, lds + 16384 + nxt * 16384 + 8192 + dstB);
      asm volatile("s_waitcnt vmcnt(3)" ::: "memory");  // cur's 3 retired
    } else {
      asm volatile("s_waitcnt vmcnt(0)" ::: "memory");  // final slab: drain
    }
    __builtin_amdgcn_sched_barrier(0);
    __builtin_amdgcn_s_barrier();      // cur complete for all waves
    __builtin_amdgcn_sched_barrier(0);

    const char* Ab = lds + cur * 8192;
    const char* Bb = lds + 16384 + cur * 16384;
    bf16x8 af[4], bfv[4];
#pragma unroll
    for (int i = 0; i < 4; ++i) {
      af[i]  = *(const bf16x8*)(Ab + aoff[i]);
      bfv[i] = *(const bf16x8*)(Bb + boff[i]);
    }
    asm volatile("s_waitcnt lgkmcnt(0)" ::: "memory");
    __builtin_amdgcn_sched_barrier(0);
    __builtin_amdgcn_s_setprio(1);
#pragma unroll
    for (int mi = 0; mi < 4; ++mi)
#pragma unroll
      for (int ni = 0; ni < 4; ++ni)
        acc[mi][ni] = __builtin_amdgcn_mfma_f32_16x16x32_bf16(
            af[mi], bfv[ni], acc[mi][ni], 0, 0, 0);
    __builtin_amdgcn_s_setprio(0);
    __builtin_amdgcn_sched_barrier(0);
    __builtin_amdgcn_s_barrier();      // readers done; cur may be overwritten
    __builtin_amdgcn_sched_barrier(0);
    cur = nxt;
  }
}

// ---------------------------------------------------------------------------
// R16 fat 256x256 core (BK=64, 128KB LDS, counted vmcnt(8)) -- kept for
// scores, whose 144-block grid is exactly 1 clean round of fat blocks.
// ---------------------------------------------------------------------------
__device__ __forceinline__ void gemm256_core(
    const bf16_t* __restrict__ A, int lda,
    const bf16_t* __restrict__ B, int ldb,
    int m0, int n0, int kEnd,
    char* lds, f32x4 acc[8][4])
{
  const int tid  = threadIdx.x;
  const int lane = tid & 63;
  const int wave = tid >> 6;           // 0..7
  const int wm = (wave >> 2) * 128;    // 0 / 128
  const int wn = (wave & 3) * 64;      // 0 / 64 / 128 / 192
  const int fr = lane & 15;
  const int ck = lane >> 4;            // 16B chunk within 32-k slice

  const int srow = tid >> 3;           // 0..63
  const int sch  = tid & 7;
  const int kgs  = (sch ^ (srow & 7)) * 8;   // inverse-swizzled k elem offset
  const int sdst = srow * 128 + sch * 16;    // linear LDS dest

  const bf16_t* Ar = A + (size_t)(m0 + srow) * lda + kgs;
  const bf16_t* Br = B + (size_t)(n0 + srow) * ldb + kgs;

  int aoffs[8], boffs[4];
#pragma unroll
  for (int mi = 0; mi < 8; ++mi) {
    const int ra = wm + mi * 16 + fr;
    aoffs[mi] = ra * 128 + ((ck ^ (ra & 7)) * 16);
  }
#pragma unroll
  for (int ni = 0; ni < 4; ++ni) {
    const int rb = wn + ni * 16 + fr;
    boffs[ni] = rb * 128 + ((ck ^ (rb & 7)) * 16);
  }

#pragma unroll
  for (int j = 0; j < 4; ++j) {
    gld_lds16(Ar + (size_t)(j * 64) * lda, lds + j * 8192 + sdst);
    gld_lds16(Br + (size_t)(j * 64) * ldb, lds + 65536 + j * 8192 + sdst);
  }

  const int NK = kEnd >> 6;
  int cur = 0;
  for (int t = 0; t < NK; ++t) {
    const int nxt = cur ^ 1;
    if (t + 1 < NK) {
      const bf16_t* An = Ar + (t + 1) * 64;
      const bf16_t* Bn = Br + (t + 1) * 64;
#pragma unroll
      for (int j = 0; j < 4; ++j) {
        gld_lds16(An + (size_t)(j * 64) * lda, lds + nxt * 32768 + j * 8192 + sdst);
        gld_lds16(Bn + (size_t)(j * 64) * ldb, lds + 65536 + nxt * 32768 + j * 8192 + sdst);
      }
      asm volatile("s_waitcnt vmcnt(8)" ::: "memory");
    } else {
      asm volatile("s_waitcnt vmcnt(0)" ::: "memory");
    }
    __builtin_amdgcn_sched_barrier(0);
    __builtin_amdgcn_s_barrier();
    __builtin_amdgcn_sched_barrier(0);

    const char* Ab = lds + cur * 32768;
    const char* Bb = lds + 65536 + cur * 32768;
#pragma unroll
    for (int ks = 0; ks < 2; ++ks) {
      bf16x8 af[8], bfv[4];
#pragma unroll
      for (int mi = 0; mi < 8; ++mi)
        af[mi] = *(const bf16x8*)(Ab + (aoffs[mi] ^ (ks * 64)));
#pragma unroll
      for (int ni = 0; ni < 4; ++ni)
        bfv[ni] = *(const bf16x8*)(Bb + (boffs[ni] ^ (ks * 64)));
      asm volatile("s_waitcnt lgkmcnt(0)" ::: "memory");
      __builtin_amdgcn_sched_barrier(0);
      __builtin_amdgcn_s_setprio(1);
#pragma unroll
      for (int mi = 0; mi < 8; ++mi)
#pragma unroll
        for (int ni = 0; ni < 4; ++ni)
          acc[mi][ni] = __builtin_amdgcn_mfma_f32_16x16x32_bf16(
              af[mi], bfv[ni], acc[mi][ni], 0, 0, 0);
      __builtin_amdgcn_s_setprio(0);
    }
    asm volatile("s_waitcnt lgkmcnt(0)" ::: "memory");
    __builtin_amdgcn_sched_barrier(0);
    __builtin_amdgcn_s_barrier();
    __builtin_amdgcn_sched_barrier(0);
    cur = nxt;
  }
}

// ---------------------------------------------------------------------------
// 128x128 4-wave core (R6 counted-vmcnt) -- kept for pv (512 balanced blocks).
// ---------------------------------------------------------------------------
__device__ __forceinline__ void gemm_bt_core(
    const bf16_t* __restrict__ A, int lda,
    const bf16_t* __restrict__ B, int ldb,
    int m0, int n0, int kBeg, int kEnd,
    bf16_t* As, bf16_t* Bs, f32x4 acc[4][4])
{
  const int lane = threadIdx.x & 63;
  const int wave = threadIdx.x >> 6;
  const int wm = (wave >> 1) * 64;
  const int wn = (wave & 1) * 64;
  const int fr = lane & 15;
  const int ck = lane >> 4;

  const int off0 = wave * 2048 + lane * 16;
  const int row0 = wave * 32 + (lane >> 2);
  const int row1 = row0 + 16;
  const int kg   = ((lane & 3) ^ ((row0 >> 1) & 3)) * 8;

  const bf16_t* Ar0 = A + (size_t)(m0 + row0) * lda + kg;
  const bf16_t* Ar1 = A + (size_t)(m0 + row1) * lda + kg;
  const bf16_t* Br0 = B + (size_t)(n0 + row0) * ldb + kg;
  const bf16_t* Br1 = B + (size_t)(n0 + row1) * ldb + kg;

  int aoff[4], boff[4];
#pragma unroll
  for (int i = 0; i < 4; ++i) {
    const int ra = wm + i * 16 + fr;
    const int rb = wn + i * 16 + fr;
    aoff[i] = ra * 64 + ((ck ^ ((ra >> 1) & 3)) * 16);
    boff[i] = rb * 64 + ((ck ^ ((rb >> 1) & 3)) * 16);
  }

  gld_lds16(Ar0 + kBeg, (char*)As + off0);
  gld_lds16(Ar1 + kBeg, (char*)As + off0 + 1024);
  gld_lds16(Br0 + kBeg, (char*)Bs + off0);
  gld_lds16(Br1 + kBeg, (char*)Bs + off0 + 1024);

  int cur = 0;
  for (int kt = kBeg; kt < kEnd; kt += 32) {
    const int nxt = cur ^ 1;
    if (kt + 32 < kEnd) {
      gld_lds16(Ar0 + kt + 32, (char*)As + nxt * 8192 + off0);
      gld_lds16(Ar1 + kt + 32, (char*)As + nxt * 8192 + off0 + 1024);
      gld_lds16(Br0 + kt + 32, (char*)Bs + nxt * 8192 + off0);
      gld_lds16(Br1 + kt + 32, (char*)Bs + nxt * 8192 + off0 + 1024);
      asm volatile("s_waitcnt vmcnt(4)" ::: "memory");
    } else {
      asm volatile("s_waitcnt vmcnt(0)" ::: "memory");
    }
    __builtin_amdgcn_sched_barrier(0);
    __builtin_amdgcn_s_barrier();
    __builtin_amdgcn_sched_barrier(0);

    bf16x8 af[4], bfv[4];
#pragma unroll
    for (int mi = 0; mi < 4; ++mi)
      af[mi] = *(const bf16x8*)((char*)As + cur * 8192 + aoff[mi]);
#pragma unroll
    for (int ni = 0; ni < 4; ++ni)
      bfv[ni] = *(const bf16x8*)((char*)Bs + cur * 8192 + boff[ni]);
    __builtin_amdgcn_s_setprio(1);
#pragma unroll
    for (int mi = 0; mi < 4; ++mi)
#pragma unroll
      for (int ni = 0; ni < 4; ++ni)
        acc[mi][ni] = __builtin_amdgcn_mfma_f32_16x16x32_bf16(
            af[mi], bfv[ni], acc[mi][ni], 0, 0, 0);
    __builtin_amdgcn_s_setprio(0);

    asm volatile("s_waitcnt lgkmcnt(0)" ::: "memory");
    __builtin_amdgcn_sched_barrier(0);
    __builtin_amdgcn_s_barrier();
    __builtin_amdgcn_sched_barrier(0);
    cur = nxt;
  }
}

// ---------------------------------------------------------------------------
// 1) QKV, thin tiles (R18). 768 uniform 128x256 blocks = EXACTLY 3 rounds
// (R7's fat grid was 384 blocks / 1.5 rounds -> 25% idle). 48KB LDS allows
// 2+ blocks/CU co-residency -> cross-block TLP. bid: z = bid>>8, tile
// t = bid&255: mt = t>>2 (128-row), nt = t&3 (256-col). z==2 writes
// Vt[b][d][s] directly via 4-round LDS transpose.
// ---------------------------------------------------------------------------
__global__ __launch_bounds__(512) void qkv_kernel(
    const bf16_t* __restrict__ X,
    const bf16_t* __restrict__ Wq, const bf16_t* __restrict__ Wk,
    const bf16_t* __restrict__ Wv,
    bf16_t* __restrict__ Q, bf16_t* __restrict__ K, bf16_t* __restrict__ Vt)
{
  __shared__ bf16_t smem[24576];             // 48 KB
  const int bid = blockIdx.x;
  const int z   = bid >> 8;
  const int t   = bid & 255;
  const int m0  = (t >> 2) * 128;
  const int n0  = (t & 3) * 256;
  const bf16_t* W = (z == 0) ? Wq : (z == 1) ? Wk : Wv;

  f32x4 acc[4][4] = {};
  gemm_thin_core(X, 1024, W, 1024, m0, n0, 1024, (char*)smem, acc);

  const int tid  = threadIdx.x;
  const int lane = tid & 63;
  const int wave = tid >> 6;
  const int wm = (wave >> 2) * 64, wn = (wave & 3) * 64;

  if (z < 2) {
    bf16_t* Out = z ? K : Q;
#pragma unroll
    for (int mi = 0; mi < 4; ++mi)
#pragma unroll
      for (int r = 0; r < 4; ++r) {
        const int row = m0 + wm + mi * 16 + (lane >> 4) * 4 + r;
#pragma unroll
        for (int ni = 0; ni < 4; ++ni) {
          const int col = n0 + wn + ni * 16 + (lane & 15);
          Out[(size_t)row * 1024 + col] = (bf16_t)acc[mi][ni][r];
        }
      }
  } else {
    // Vt[b][d][s]: b = m0>>11, s-range = (m0&2047)..+127, d-range = n0..+255
    const int b  = m0 >> 11;
    const int s0 = m0 & 2047;
    bf16_t* Vtb = Vt + (size_t)b * 1024 * 2048;
    bf16_t (*tb)[136] = (bf16_t(*)[136])smem;  // 64*136*2 = 17.4 KB <= 48 KB
#pragma unroll
    for (int h = 0; h < 4; ++h) {              // d-quarter rounds
      __syncthreads();
      if ((wave & 3) == h) {                   // waves h, h+4 own cols h*64..+63
#pragma unroll
        for (int mi = 0; mi < 4; ++mi)
#pragma unroll
          for (int ni = 0; ni < 4; ++ni) {
            const int c    = ni * 16 + (lane & 15);          // d-local 0..63
            const int rowl = wm + mi * 16 + (lane >> 4) * 4; // s-local 0..124
            bf16x4 v;
            v[0] = (bf16_t)acc[mi][ni][0]; v[1] = (bf16_t)acc[mi][ni][1];
            v[2] = (bf16_t)acc[mi][ni][2]; v[3] = (bf16_t)acc[mi][ni][3];
            *(bf16x4*)&tb[c][rowl] = v;        // 8B LDS write, aligned
          }
      }
      __syncthreads();
      // store 64 d-rows x 128 s: 1024 8-elem chunks over 512 threads
#pragma unroll
      for (int i = 0; i < 2; ++i) {
        const int idx = tid + 512 * i;         // 0..1023
        const int d   = idx >> 4;              // 0..63
        const int ch  = idx & 15;              // 8-elem chunk (128/8 = 16)
        bf16x8 vv = *(const bf16x8*)&tb[d][ch * 8];
        *(bf16x8*)(Vtb + (size_t)(n0 + h * 64 + d) * 2048 + s0 + ch * 8) = vv;
      }
    }
  }
}

// ---------------------------------------------------------------------------
// 3) Fused scores+exp, 256q x 256k causal tiles, fat core. 144 uniform
// full-K blocks = 1 clean round. P = exp((Q.K)/32) unnorm bf16; lp written
// per-128-k slice (2kt, 2kt+1) as pv/lsum expect.
// ---------------------------------------------------------------------------
__global__ __launch_bounds__(512) void scores_exp_kernel(
    const bf16_t* __restrict__ Q, const bf16_t* __restrict__ K,
    bf16_t* __restrict__ P, float* __restrict__ partials)
{
  const int kt = blockIdx.x;          // k-tile (256 wide)
  const int mt = blockIdx.y;          // q-tile (256 wide)
  if (kt > mt) return;                // fully masked tile
  const int m0 = mt * 256;
  const int n0 = kt * 256;
  __shared__ bf16_t smem[65536];
  const int batch = blockIdx.z;
  const bf16_t* Qb = Q + (size_t)batch * 2048 * 1024;
  const bf16_t* Kb = K + (size_t)batch * 2048 * 1024;
  bf16_t* Pb = P + (size_t)batch * 2048 * 2048;
  float* lp  = partials + (size_t)batch * 16 * 2048;

  f32x4 acc[8][4] = {};
  gemm256_core(Qb, 1024, Kb, 1024, m0, n0, 1024, (char*)smem, acc);

  const int tid  = threadIdx.x;
  const int lane = tid & 63;
  const int wave = tid >> 6;
  const int wm = (wave >> 2) * 128, wn = (wave & 3) * 64;
  float (*rowsum)[256] = (float(*)[256])smem;  // reuse LDS (post-loop barrier)
  const float c = 0.04508422f;        // log2(e)/32
#pragma unroll
  for (int mi = 0; mi < 8; ++mi)
#pragma unroll
    for (int r = 0; r < 4; ++r) {
      const int lrow = wm + mi * 16 + (lane >> 4) * 4 + r;   // 0..255
      const int row  = m0 + lrow;
      float rs = 0.f;
#pragma unroll
      for (int ni = 0; ni < 4; ++ni) {
        const int col = n0 + wn + ni * 16 + (lane & 15);
        float p = exp2f(acc[mi][ni][r] * c);
        if (col > row) p = 0.f;
        const bf16_t pb = (bf16_t)p;
        Pb[(size_t)row * 2048 + col] = pb;
        rs += (float)pb;              // sum the rounded value pv reads
      }
      rs += __shfl_xor(rs, 1);
      rs += __shfl_xor(rs, 2);
      rs += __shfl_xor(rs, 4);
      rs += __shfl_xor(rs, 8);
      if ((lane & 15) == 0) rowsum[wave & 3][lrow] = rs;  // col-quarter part
    }
  __syncthreads();
  {
    const int row = tid & 255;        // 0..255
    const int s   = tid >> 8;         // 0..1 -> 128-k slice within tile
    lp[(size_t)(2 * kt + s) * 2048 + m0 + row] =
        rowsum[2 * s][row] + rowsum[2 * s + 1][row];
  }
}

// ---------------------------------------------------------------------------
// 3.5) Row-sum finalize: Linv[z][row] = 1 / sum_{kt<=row>>7} lp[z][kt][row].
// ---------------------------------------------------------------------------
__global__ __launch_bounds__(256) void lsum_kernel(
    const float* __restrict__ partials, float* __restrict__ Linv)
{
  const int id  = blockIdx.x * 256 + threadIdx.x;  // z*2048 + row
  const int z   = id >> 11;
  const int row = id & 2047;
  const float* lp = partials + (size_t)z * 16 * 2048;
  const int tmax = row >> 7;
  float l = 0.f;
  for (int kt = 0; kt <= tmax; ++kt) l += lp[kt * 2048 + row];
  Linv[id] = 1.f / l;
}

// ---------------------------------------------------------------------------
// 4) PV, 128x128-tile GEMM, all 4 batches (512 blocks = 2/CU, all resident).
// mt pairing keeps each CU's co-hosted pair at exactly 17 k128-tiles.
// Causality: kEnd = m0+128; scores wrote+masked exactly that range.
// ---------------------------------------------------------------------------
__global__ __launch_bounds__(256) void pv_kernel(
    const bf16_t* __restrict__ P, const bf16_t* __restrict__ Vt,
    const float* __restrict__ Linv, float* __restrict__ out)
{
  __shared__ bf16_t smem[4 * 128 * 32];
  bf16_t* As = smem;
  bf16_t* Bs = smem + 2 * 128 * 32;
  const int zb = blockIdx.z;
  const int mt = ((zb >> 1) & 1) ? (15 - blockIdx.y) : blockIdx.y;
  const int m0 = mt * 128;
  const int n0 = blockIdx.x * 128;             // d
  const bf16_t* Pb  = P  + (size_t)zb * 2048 * 2048;
  const bf16_t* Vtb = Vt + (size_t)zb * 1024 * 2048;
  const float* li = Linv + (size_t)zb * 2048;
  float* ob = out + (size_t)zb * 2048 * 1024;

  f32x4 acc[4][4] = {};
  gemm_bt_core(Pb, 2048, Vtb, 2048, m0, n0, 0, m0 + 128, As, Bs, acc);

  const int lane = threadIdx.x & 63;
  const int wave = threadIdx.x >> 6;
  const int wm = (wave >> 1) * 64, wn = (wave & 1) * 64;
#pragma unroll
  for (int mi = 0; mi < 4; ++mi)
#pragma unroll
    for (int r = 0; r < 4; ++r) {
      const int row = m0 + wm + mi * 16 + (lane >> 4) * 4 + r;
      const float inv = li[row];
#pragma unroll
      for (int ni = 0; ni < 2; ++ni) {
        const int col = n0 + wn + ni * 16 + (lane & 15);
        ob[(size_t)row * 1024 + col] = acc[mi][ni][r] * inv;
      }
#pragma unroll
      for (int ni = 2; ni < 4; ++ni) {
        const int col = n0 + wn + ni * 16 + (lane & 15);
        ob[(size_t)row * 1024 + col] = acc[mi][ni][r] * inv;
      }
    }
}

// ---------------------------------------------------------------------------
// R18 workspace (identical to R7; V/vt eliminated):
//   [0,16M)    Q     (dead after scores)
//   [16,32M)   K     (dead after scores)
//   [32,48M)   Vt    (written directly by qkv z=2)
//   [48,64M)   Xc    (dead after qkv)  \
//   [64,70M)   W     (dead after qkv)   }- P[4 batches, 32M) = [48,80M)
//   [70,80M)   fresh P tail            /
//   [80,80.5M) Lp;  [80.5M,..) Linv
// Order: convert -> qkv(thin,768) -> scores(fat,144) -> lsum -> pv.
// ---------------------------------------------------------------------------
extern "C" void kernel_launch(void* const* d_in, const int* in_sizes, int n_in,
                              void* d_out, int out_size, void* d_ws, size_t ws_size,
                              hipStream_t stream) {
  const float* X  = (const float*)d_in[0];
  const float* Wq = (const float*)d_in[1];
  const float* Wk = (const float*)d_in[2];
  const float* Wv = (const float*)d_in[3];
  float* out = (float*)d_out;
  char* ws = (char*)d_ws;

  const size_t MB = 1024 * 1024;
  bf16_t* Q    = (bf16_t*)(ws + 0 * MB);
  bf16_t* K    = (bf16_t*)(ws + 16 * MB);
  bf16_t* Vt   = (bf16_t*)(ws + 32 * MB);
  bf16_t* Xc   = (bf16_t*)(ws + 48 * MB);
  bf16_t* Wqc  = (bf16_t*)(ws + 64 * MB);
  bf16_t* Wkc  = (bf16_t*)(ws + 66 * MB);
  bf16_t* Wvc  = (bf16_t*)(ws + 68 * MB);
  bf16_t* P    = (bf16_t*)(ws + 48 * MB);   // aliases Xc+W, extends to 80M
  float*  Lp   = (float*)(ws + 80 * MB);
  float*  Linv = (float*)(ws + 80 * MB + 512 * 1024);

  convert_all_kernel<<<dim3(5632), 256, 0, stream>>>(X, Wq, Wk, Wv, Xc, Wqc, Wkc, Wvc);
  qkv_kernel<<<dim3(768), 512, 0, stream>>>(Xc, Wqc, Wkc, Wvc, Q, K, Vt);
  scores_exp_kernel<<<dim3(8, 8, 4), 512, 0, stream>>>(Q, K, P, Lp);
  lsum_kernel<<<dim3(32), 256, 0, stream>>>(Lp, Linv);
  pv_kernel<<<dim3(8, 16, 4), 256, 0, stream>>>(P, Vt, Linv, out);
}

// Round 9
// 225.287 us; speedup vs baseline: 1.1772x; 1.0275x over previous
//
#include <hip/hip_runtime.h>
#include <stdint.h>

typedef __bf16 bf16_t;
typedef __bf16 bf16x4 __attribute__((ext_vector_type(4)));
typedef __bf16 bf16x8 __attribute__((ext_vector_type(8)));
typedef float  f32x4  __attribute__((ext_vector_type(4)));

#define AS1 __attribute__((address_space(1)))
#define AS3 __attribute__((address_space(3)))

__device__ __forceinline__ void gld_lds16(const bf16_t* g, void* s) {
  // async global->LDS, 16 bytes per lane; HW dest = wave-uniform base + lane*16
  __builtin_amdgcn_global_load_lds((const AS1 uint32_t*)g, (AS3 uint32_t*)s, 16, 0, 0);
}

// ---------------------------------------------------------------------------
// 0) fp32 -> bf16 canonicalization, all 4 tensors in ONE dispatch.
// ---------------------------------------------------------------------------
__global__ __launch_bounds__(256) void convert_all_kernel(
    const float* __restrict__ X,  const float* __restrict__ Wq,
    const float* __restrict__ Wk, const float* __restrict__ Wv,
    bf16_t* __restrict__ Xc, bf16_t* __restrict__ Wqc,
    bf16_t* __restrict__ Wkc, bf16_t* __restrict__ Wvc) {
  const int blk = blockIdx.x;
  const float* src; bf16_t* dst; int base;
  if (blk < 4096)      { src = X;  dst = Xc;  base = 0;    }
  else if (blk < 4608) { src = Wq; dst = Wqc; base = 4096; }
  else if (blk < 5120) { src = Wk; dst = Wkc; base = 4608; }
  else                 { src = Wv; dst = Wvc; base = 5120; }
  const int i = ((blk - base) * 256 + threadIdx.x) * 8;
  const float4 a = ((const float4*)(src + i))[0];
  const float4 b = ((const float4*)(src + i))[1];
  bf16x8 v;
  v[0] = (bf16_t)a.x; v[1] = (bf16_t)a.y; v[2] = (bf16_t)a.z; v[3] = (bf16_t)a.w;
  v[4] = (bf16_t)b.x; v[5] = (bf16_t)b.y; v[6] = (bf16_t)b.z; v[7] = (bf16_t)b.w;
  *(bf16x8*)(dst + i) = v;
}

// ---------------------------------------------------------------------------
// THIN core: 128x256 tile, BK=32, 8 waves (512 thr), wave grid 2M x 4N,
// per-wave 64x64 = acc[4][4]. Double-buffered: As 2x8KB + Bs 2x16KB = 48 KB.
// Counted vmcnt(3) (R6 discipline). R9 FIX: swizzle slot = ck^((row>>1)&3)
// (R8's (row&3) gave 4-way conflicts on even rows -> 6.5M conflict cycles;
// the (row>>1)&3 class measured ~0.2M in R6/R7). Staged via inverse-swizzled
// global source (linear LDS dest, rule #21).
// ---------------------------------------------------------------------------
__device__ __forceinline__ void gemm_thin_core(
    const bf16_t* __restrict__ A, int lda,
    const bf16_t* __restrict__ B, int ldb,
    int m0, int n0, int kEnd,
    char* lds, f32x4 acc[4][4])
{
  const int tid  = threadIdx.x;
  const int lane = tid & 63;
  const int wave = tid >> 6;           // 0..7
  const int wm = (wave >> 2) * 64;     // 0 / 64
  const int wn = (wave & 3) * 64;      // 0 / 64 / 128 / 192
  const int fr = lane & 15;
  const int ck = lane >> 4;            // 16B chunk of the 32-k slice

  // staging: thread t -> A slot (row=t>>2, ch=t&3); B rows t>>2 and t>>2+128
  const int srow = tid >> 2;           // 0..127
  const int sch  = tid & 3;
  const int kg   = (sch ^ ((srow >> 1) & 3)) * 8;  // inverse-swizzled k off
  const int dstA = srow * 64 + sch * 16;           // bytes within 8KB buffer
  const int dstB = dstA;

  const bf16_t* Ar  = A + (size_t)(m0 + srow) * lda + kg;
  const bf16_t* Br0 = B + (size_t)(n0 + srow) * ldb + kg;
  const bf16_t* Br1 = B + (size_t)(n0 + srow + 128) * ldb + kg;  // ((srow+128)>>1)&3 == (srow>>1)&3

  int aoff[4], boff[4];
#pragma unroll
  for (int i = 0; i < 4; ++i) {
    const int ra = wm + i * 16 + fr;           // 0..127
    const int rb = wn + i * 16 + fr;           // 0..255
    aoff[i] = ra * 64 + ((ck ^ ((ra >> 1) & 3)) * 16);
    boff[i] = rb * 64 + ((ck ^ ((rb >> 1) & 3)) * 16);
  }

  // LDS map: [0,16K) = As dbuf (2x8K); [16K,48K) = Bs dbuf (2x16K)
  gld_lds16(Ar, lds + dstA);
  gld_lds16(Br0, lds + 16384 + dstB);
  gld_lds16(Br1, lds + 16384 + 8192 + dstB);

  const int NK = kEnd >> 5;
  int cur = 0;
  for (int t = 0; t < NK; ++t) {
    const int nxt = cur ^ 1;
    if (t + 1 < NK) {                  // STAGE next slab first (depth-1)
      const int ko = (t + 1) * 32;
      gld_lds16(Ar + ko, lds + nxt * 8192 + dstA);
      gld_lds16(Br0 + ko, lds + 16384 + nxt * 16384 + dstB);
      gld_lds16(Br1 + ko, lds + 16384 + nxt * 16384 + 8192 + dstB);
      asm volatile("s_waitcnt vmcnt(3)" ::: "memory");  // cur's 3 retired
    } else {
      asm volatile("s_waitcnt vmcnt(0)" ::: "memory");  // final slab: drain
    }
    __builtin_amdgcn_sched_barrier(0);
    __builtin_amdgcn_s_barrier();      // cur complete for all waves
    __builtin_amdgcn_sched_barrier(0);

    const char* Ab = lds + cur * 8192;
    const char* Bb = lds + 16384 + cur * 16384;
    bf16x8 af[4], bfv[4];
#pragma unroll
    for (int i = 0; i < 4; ++i) {
      af[i]  = *(const bf16x8*)(Ab + aoff[i]);
      bfv[i] = *(const bf16x8*)(Bb + boff[i]);
    }
    asm volatile("s_waitcnt lgkmcnt(0)" ::: "memory");
    __builtin_amdgcn_sched_barrier(0);
    __builtin_amdgcn_s_setprio(1);
#pragma unroll
    for (int mi = 0; mi < 4; ++mi)
#pragma unroll
      for (int ni = 0; ni < 4; ++ni)
        acc[mi][ni] = __builtin_amdgcn_mfma_f32_16x16x32_bf16(
            af[mi], bfv[ni], acc[mi][ni], 0, 0, 0);
    __builtin_amdgcn_s_setprio(0);
    __builtin_amdgcn_sched_barrier(0);
    __builtin_amdgcn_s_barrier();      // readers done; cur may be overwritten
    __builtin_amdgcn_sched_barrier(0);
    cur = nxt;
  }
}

// ---------------------------------------------------------------------------
// 128x128 4-wave core (R6 counted-vmcnt) -- kept for pv (512 balanced blocks).
// ---------------------------------------------------------------------------
__device__ __forceinline__ void gemm_bt_core(
    const bf16_t* __restrict__ A, int lda,
    const bf16_t* __restrict__ B, int ldb,
    int m0, int n0, int kBeg, int kEnd,
    bf16_t* As, bf16_t* Bs, f32x4 acc[4][4])
{
  const int lane = threadIdx.x & 63;
  const int wave = threadIdx.x >> 6;
  const int wm = (wave >> 1) * 64;
  const int wn = (wave & 1) * 64;
  const int fr = lane & 15;
  const int ck = lane >> 4;

  const int off0 = wave * 2048 + lane * 16;
  const int row0 = wave * 32 + (lane >> 2);
  const int row1 = row0 + 16;
  const int kg   = ((lane & 3) ^ ((row0 >> 1) & 3)) * 8;

  const bf16_t* Ar0 = A + (size_t)(m0 + row0) * lda + kg;
  const bf16_t* Ar1 = A + (size_t)(m0 + row1) * lda + kg;
  const bf16_t* Br0 = B + (size_t)(n0 + row0) * ldb + kg;
  const bf16_t* Br1 = B + (size_t)(n0 + row1) * ldb + kg;

  int aoff[4], boff[4];
#pragma unroll
  for (int i = 0; i < 4; ++i) {
    const int ra = wm + i * 16 + fr;
    const int rb = wn + i * 16 + fr;
    aoff[i] = ra * 64 + ((ck ^ ((ra >> 1) & 3)) * 16);
    boff[i] = rb * 64 + ((ck ^ ((rb >> 1) & 3)) * 16);
  }

  gld_lds16(Ar0 + kBeg, (char*)As + off0);
  gld_lds16(Ar1 + kBeg, (char*)As + off0 + 1024);
  gld_lds16(Br0 + kBeg, (char*)Bs + off0);
  gld_lds16(Br1 + kBeg, (char*)Bs + off0 + 1024);

  int cur = 0;
  for (int kt = kBeg; kt < kEnd; kt += 32) {
    const int nxt = cur ^ 1;
    if (kt + 32 < kEnd) {
      gld_lds16(Ar0 + kt + 32, (char*)As + nxt * 8192 + off0);
      gld_lds16(Ar1 + kt + 32, (char*)As + nxt * 8192 + off0 + 1024);
      gld_lds16(Br0 + kt + 32, (char*)Bs + nxt * 8192 + off0);
      gld_lds16(Br1 + kt + 32, (char*)Bs + nxt * 8192 + off0 + 1024);
      asm volatile("s_waitcnt vmcnt(4)" ::: "memory");
    } else {
      asm volatile("s_waitcnt vmcnt(0)" ::: "memory");
    }
    __builtin_amdgcn_sched_barrier(0);
    __builtin_amdgcn_s_barrier();
    __builtin_amdgcn_sched_barrier(0);

    bf16x8 af[4], bfv[4];
#pragma unroll
    for (int mi = 0; mi < 4; ++mi)
      af[mi] = *(const bf16x8*)((char*)As + cur * 8192 + aoff[mi]);
#pragma unroll
    for (int ni = 0; ni < 4; ++ni)
      bfv[ni] = *(const bf16x8*)((char*)Bs + cur * 8192 + boff[ni]);
    __builtin_amdgcn_s_setprio(1);
#pragma unroll
    for (int mi = 0; mi < 4; ++mi)
#pragma unroll
      for (int ni = 0; ni < 4; ++ni)
        acc[mi][ni] = __builtin_amdgcn_mfma_f32_16x16x32_bf16(
            af[mi], bfv[ni], acc[mi][ni], 0, 0, 0);
    __builtin_amdgcn_s_setprio(0);

    asm volatile("s_waitcnt lgkmcnt(0)" ::: "memory");
    __builtin_amdgcn_sched_barrier(0);
    __builtin_amdgcn_s_barrier();
    __builtin_amdgcn_sched_barrier(0);
    cur = nxt;
  }
}

// ---------------------------------------------------------------------------
// 1) QKV, thin tiles. 768 uniform 128x256 blocks = exactly 3 rounds; 48KB
// LDS -> 2-3 blocks/CU co-residency. z==2 writes Vt[b][d][s] directly.
// ---------------------------------------------------------------------------
__global__ __launch_bounds__(512) void qkv_kernel(
    const bf16_t* __restrict__ X,
    const bf16_t* __restrict__ Wq, const bf16_t* __restrict__ Wk,
    const bf16_t* __restrict__ Wv,
    bf16_t* __restrict__ Q, bf16_t* __restrict__ K, bf16_t* __restrict__ Vt)
{
  __shared__ bf16_t smem[24576];             // 48 KB
  const int bid = blockIdx.x;
  const int z   = bid >> 8;
  const int t   = bid & 255;
  const int m0  = (t >> 2) * 128;
  const int n0  = (t & 3) * 256;
  const bf16_t* W = (z == 0) ? Wq : (z == 1) ? Wk : Wv;

  f32x4 acc[4][4] = {};
  gemm_thin_core(X, 1024, W, 1024, m0, n0, 1024, (char*)smem, acc);

  const int tid  = threadIdx.x;
  const int lane = tid & 63;
  const int wave = tid >> 6;
  const int wm = (wave >> 2) * 64, wn = (wave & 3) * 64;

  if (z < 2) {
    bf16_t* Out = z ? K : Q;
#pragma unroll
    for (int mi = 0; mi < 4; ++mi)
#pragma unroll
      for (int r = 0; r < 4; ++r) {
        const int row = m0 + wm + mi * 16 + (lane >> 4) * 4 + r;
#pragma unroll
        for (int ni = 0; ni < 4; ++ni) {
          const int col = n0 + wn + ni * 16 + (lane & 15);
          Out[(size_t)row * 1024 + col] = (bf16_t)acc[mi][ni][r];
        }
      }
  } else {
    // Vt[b][d][s]: b = m0>>11, s-range = (m0&2047)..+127, d-range = n0..+255
    const int b  = m0 >> 11;
    const int s0 = m0 & 2047;
    bf16_t* Vtb = Vt + (size_t)b * 1024 * 2048;
    bf16_t (*tb)[136] = (bf16_t(*)[136])smem;  // 64*136*2 = 17.4 KB <= 48 KB
#pragma unroll
    for (int h = 0; h < 4; ++h) {              // d-quarter rounds
      __syncthreads();
      if ((wave & 3) == h) {                   // waves h, h+4 own cols h*64..+63
#pragma unroll
        for (int mi = 0; mi < 4; ++mi)
#pragma unroll
          for (int ni = 0; ni < 4; ++ni) {
            const int c    = ni * 16 + (lane & 15);          // d-local 0..63
            const int rowl = wm + mi * 16 + (lane >> 4) * 4; // s-local 0..124
            bf16x4 v;
            v[0] = (bf16_t)acc[mi][ni][0]; v[1] = (bf16_t)acc[mi][ni][1];
            v[2] = (bf16_t)acc[mi][ni][2]; v[3] = (bf16_t)acc[mi][ni][3];
            *(bf16x4*)&tb[c][rowl] = v;        // 8B LDS write, aligned
          }
      }
      __syncthreads();
      // store 64 d-rows x 128 s: 1024 8-elem chunks over 512 threads
#pragma unroll
      for (int i = 0; i < 2; ++i) {
        const int idx = tid + 512 * i;         // 0..1023
        const int d   = idx >> 4;              // 0..63
        const int ch  = idx & 15;              // 8-elem chunk
        bf16x8 vv = *(const bf16x8*)&tb[d][ch * 8];
        *(bf16x8*)(Vtb + (size_t)(n0 + h * 64 + d) * 2048 + s0 + ch * 8) = vv;
      }
    }
  }
}

// ---------------------------------------------------------------------------
// 3) Fused scores+exp, R9: THIN 128q x 256k causal tiles (uniform K=1024 ->
// no imbalance). 288 active blocks (was 144 fat = 44% of CUs idle) with
// 2-3/CU co-residency. P = exp((Q.K)/32) unnorm bf16; lp written per-128-k
// slice (2nt, 2nt+1) exactly as lsum/pv expect. Diagonal mask col>row; for
// even mt the upper 128-col half is all-zero and never read downstream.
// ---------------------------------------------------------------------------
__global__ __launch_bounds__(512) void scores_exp_kernel(
    const bf16_t* __restrict__ Q, const bf16_t* __restrict__ K,
    bf16_t* __restrict__ P, float* __restrict__ partials)
{
  const int nt = blockIdx.x;          // k-tile (256 wide), 0..7
  const int mt = blockIdx.y;          // q-tile (128 rows), 0..15
  if (nt > (mt >> 1)) return;         // fully masked tile
  const int m0 = mt * 128;
  const int n0 = nt * 256;
  __shared__ bf16_t smem[24576];      // 48 KB (core dbuf; reused for rowsum)
  const int batch = blockIdx.z;
  const bf16_t* Qb = Q + (size_t)batch * 2048 * 1024;
  const bf16_t* Kb = K + (size_t)batch * 2048 * 1024;
  bf16_t* Pb = P + (size_t)batch * 2048 * 2048;
  float* lp  = partials + (size_t)batch * 16 * 2048;

  f32x4 acc[4][4] = {};
  gemm_thin_core(Qb, 1024, Kb, 1024, m0, n0, 1024, (char*)smem, acc);

  const int tid  = threadIdx.x;
  const int lane = tid & 63;
  const int wave = tid >> 6;
  const int wm = (wave >> 2) * 64, wn = (wave & 3) * 64;
  float (*rs4)[128] = (float(*)[128])smem;   // 4 col-quarters x 128 rows
  const float c = 0.04508422f;        // log2(e)/32
#pragma unroll
  for (int mi = 0; mi < 4; ++mi)
#pragma unroll
    for (int r = 0; r < 4; ++r) {
      const int lrow = wm + mi * 16 + (lane >> 4) * 4 + r;   // 0..127
      const int row  = m0 + lrow;
      float rs = 0.f;
#pragma unroll
      for (int ni = 0; ni < 4; ++ni) {
        const int col = n0 + wn + ni * 16 + (lane & 15);
        float p = exp2f(acc[mi][ni][r] * c);
        if (col > row) p = 0.f;
        const bf16_t pb = (bf16_t)p;
        Pb[(size_t)row * 2048 + col] = pb;
        rs += (float)pb;              // sum the rounded value pv reads
      }
      rs += __shfl_xor(rs, 1);
      rs += __shfl_xor(rs, 2);
      rs += __shfl_xor(rs, 4);
      rs += __shfl_xor(rs, 8);
      if ((lane & 15) == 0) rs4[wave & 3][lrow] = rs;  // col-quarter partial
    }
  __syncthreads();
  if (tid < 256) {
    const int row = tid & 127;        // 0..127
    const int s   = tid >> 7;         // 0..1 -> 128-k slice within 256 tile
    lp[(size_t)(2 * nt + s) * 2048 + m0 + row] =
        rs4[2 * s][row] + rs4[2 * s + 1][row];
  }
}

// ---------------------------------------------------------------------------
// 3.5) Row-sum finalize: Linv[z][row] = 1 / sum_{kt<=row>>7} lp[z][kt][row].
// ---------------------------------------------------------------------------
__global__ __launch_bounds__(256) void lsum_kernel(
    const float* __restrict__ partials, float* __restrict__ Linv)
{
  const int id  = blockIdx.x * 256 + threadIdx.x;  // z*2048 + row
  const int z   = id >> 11;
  const int row = id & 2047;
  const float* lp = partials + (size_t)z * 16 * 2048;
  const int tmax = row >> 7;
  float l = 0.f;
  for (int kt = 0; kt <= tmax; ++kt) l += lp[kt * 2048 + row];
  Linv[id] = 1.f / l;
}

// ---------------------------------------------------------------------------
// 4) PV, 128x128-tile GEMM, all 4 batches (512 blocks = 2/CU, all resident).
// mt pairing keeps each CU's co-hosted pair at exactly 17 k128-tiles.
// Causality: kEnd = m0+128; scores wrote+masked exactly that range.
// ---------------------------------------------------------------------------
__global__ __launch_bounds__(256) void pv_kernel(
    const bf16_t* __restrict__ P, const bf16_t* __restrict__ Vt,
    const float* __restrict__ Linv, float* __restrict__ out)
{
  __shared__ bf16_t smem[4 * 128 * 32];
  bf16_t* As = smem;
  bf16_t* Bs = smem + 2 * 128 * 32;
  const int zb = blockIdx.z;
  const int mt = ((zb >> 1) & 1) ? (15 - blockIdx.y) : blockIdx.y;
  const int m0 = mt * 128;
  const int n0 = blockIdx.x * 128;             // d
  const bf16_t* Pb  = P  + (size_t)zb * 2048 * 2048;
  const bf16_t* Vtb = Vt + (size_t)zb * 1024 * 2048;
  const float* li = Linv + (size_t)zb * 2048;
  float* ob = out + (size_t)zb * 2048 * 1024;

  f32x4 acc[4][4] = {};
  gemm_bt_core(Pb, 2048, Vtb, 2048, m0, n0, 0, m0 + 128, As, Bs, acc);

  const int lane = threadIdx.x & 63;
  const int wave = threadIdx.x >> 6;
  const int wm = (wave >> 1) * 64, wn = (wave & 1) * 64;
#pragma unroll
  for (int mi = 0; mi < 4; ++mi)
#pragma unroll
    for (int r = 0; r < 4; ++r) {
      const int row = m0 + wm + mi * 16 + (lane >> 4) * 4 + r;
      const float inv = li[row];
#pragma unroll
      for (int ni = 0; ni < 4; ++ni) {
        const int col = n0 + wn + ni * 16 + (lane & 15);
        ob[(size_t)row * 1024 + col] = acc[mi][ni][r] * inv;
      }
    }
}

// ---------------------------------------------------------------------------
// R9 workspace (identical layout to R7/R8):
//   [0,16M)    Q     (dead after scores)
//   [16,32M)   K     (dead after scores)
//   [32,48M)   Vt    (written directly by qkv z=2)
//   [48,80M)   P     (aliases Xc+W, both dead after qkv)
//   [80,80.5M) Lp;  [80.5M,..) Linv
// Order: convert -> qkv(thin,768) -> scores(thin,288 active) -> lsum -> pv.
// ---------------------------------------------------------------------------
extern "C" void kernel_launch(void* const* d_in, const int* in_sizes, int n_in,
                              void* d_out, int out_size, void* d_ws, size_t ws_size,
                              hipStream_t stream) {
  const float* X  = (const float*)d_in[0];
  const float* Wq = (const float*)d_in[1];
  const float* Wk = (const float*)d_in[2];
  const float* Wv = (const float*)d_in[3];
  float* out = (float*)d_out;
  char* ws = (char*)d_ws;

  const size_t MB = 1024 * 1024;
  bf16_t* Q    = (bf16_t*)(ws + 0 * MB);
  bf16_t* K    = (bf16_t*)(ws + 16 * MB);
  bf16_t* Vt   = (bf16_t*)(ws + 32 * MB);
  bf16_t* Xc   = (bf16_t*)(ws + 48 * MB);
  bf16_t* Wqc  = (bf16_t*)(ws + 64 * MB);
  bf16_t* Wkc  = (bf16_t*)(ws + 66 * MB);
  bf16_t* Wvc  = (bf16_t*)(ws + 68 * MB);
  bf16_t* P    = (bf16_t*)(ws + 48 * MB);   // aliases Xc+W, extends to 80M
  float*  Lp   = (float*)(ws + 80 * MB);
  float*  Linv = (float*)(ws + 80 * MB + 512 * 1024);

  convert_all_kernel<<<dim3(5632), 256, 0, stream>>>(X, Wq, Wk, Wv, Xc, Wqc, Wkc, Wvc);
  qkv_kernel<<<dim3(768), 512, 0, stream>>>(Xc, Wqc, Wkc, Wvc, Q, K, Vt);
  scores_exp_kernel<<<dim3(8, 16, 4), 512, 0, stream>>>(Q, K, P, Lp);
  lsum_kernel<<<dim3(32), 256, 0, stream>>>(Lp, Linv);
  pv_kernel<<<dim3(8, 16, 4), 256, 0, stream>>>(P, Vt, Linv, out);
}